// Round 10
// baseline (512.839 us; speedup 1.0000x reference)
//
#include <hip/hip_runtime.h>
#include <hip/hip_bf16.h>

typedef __hip_bfloat16 bf16;
typedef __attribute__((ext_vector_type(8))) short bf16x8;
typedef __attribute__((ext_vector_type(4))) float f32x4;

__device__ __forceinline__ void st_bf16(short* p, float v) {
    uint32_t u = __float_as_uint(v) + 0x8000u;
    *p = (short)(u >> 16);
}
__device__ __forceinline__ float bb2f(short s) {
    uint32_t u = ((uint32_t)(uint16_t)s) << 16;
    return __uint_as_float(u);
}

// ------------------------------------------------------------- prep_all ----
__global__ __launch_bounds__(256) void prep_all(
    const float* __restrict__ W000, const float* __restrict__ W110, const float* __restrict__ W220,
    const float* __restrict__ W011, const float* __restrict__ W101, const float* __restrict__ W121,
    const float* __restrict__ W211, const float* __restrict__ W111,
    const float* __restrict__ W022, const float* __restrict__ W202, const float* __restrict__ W112,
    const float* __restrict__ W222, const float* __restrict__ W212,
    const float* __restrict__ W1, const float* __restrict__ W2, const float* __restrict__ W3,
    const float* __restrict__ Wdir, bf16* __restrict__ wout,
    const float* __restrict__ xa, const float* __restrict__ xv, const float* __restrict__ xd,
    const float* __restrict__ WL0, const float* __restrict__ WL1, const float* __restrict__ WL2,
    float* __restrict__ Pa, float* __restrict__ Pv, float* __restrict__ Pd, int N, int NPB,
    const int* __restrict__ src, const int* __restrict__ dst,
    int* __restrict__ cnt_s, int* __restrict__ cnt_d, int E)
{
    int b = blockIdx.x;
    const int tid = threadIdx.x;
    if (b < 178) {
        int i = b * 256 + tid;
        if (i >= 45568) return;
        float v = 0.f;
        if (i < 4096) {
            int o = i >> 6, k = i & 63;
            if (k < 48) {
                int t = k >> 4, c = k & 15;
                const float* W = (t == 0) ? W000 : (t == 1) ? W110 : W220;
                v = W[o * 16 + c];
            }
        } else if (i < 7168) {
            int r = i - 4096, ch = r / 96, k = r % 96;
            if (k < 80) {
                int t = k >> 4, c = k & 15;
                const float* W = (t == 0) ? W011 : (t == 1) ? W101 : (t == 2) ? W121 : (t == 3) ? W211 : W111;
                v = W[ch * 16 + c];
            }
        } else if (i < 8704) {
            int r = i - 7168, ch = r / 96, k = r % 96;
            if (k < 80) {
                int t = k >> 4, c = k & 15;
                const float* W = (t == 0) ? W022 : (t == 1) ? W202 : (t == 2) ? W112 : (t == 3) ? W222 : W212;
                v = W[ch * 16 + c];
            }
        } else if (i < 16896) v = W1[i - 8704];
        else if (i < 33280) v = W2[i - 16896];
        else if (i < 41472) v = W3[i - 33280];
        else v = Wdir[i - 41472];
        wout[i] = __float2bfloat16(v);
        return;
    }
    b -= 178;
    if (b < NPB) {
        __shared__ float sxa[256], sxv[384], sxd[576];
        const int n0 = b * 4;
        if (n0 + tid / 64 < N) sxa[tid] = xa[(size_t)n0 * 64 + tid];
        for (int i = tid; i < 384; i += 256) if (n0 + i / 96 < N)  sxv[i] = xv[(size_t)n0 * 96 + i];
        for (int i = tid; i < 576; i += 256) if (n0 + i / 144 < N) sxd[i] = xd[(size_t)n0 * 144 + i];
        __syncthreads();
        for (int o = tid; o < 832; o += 256) {
            int ln = o / 208, s = o % 208;
            int n = n0 + ln;
            if (n >= N) continue;
            if (s < 16) {
                float a = 0.f;
                const float* w = WL0 + s * 64;
                const float* x = sxa + ln * 64;
                for (int d = 0; d < 64; ++d) a += w[d] * x[d];
                Pa[(size_t)n * 16 + s] = a;
            } else if (s < 64) {
                int idx = s - 16, c = idx / 3, i = idx % 3;
                float a = 0.f;
                const float* w = WL1 + c * 32;
                const float* x = sxv + ln * 96;
                for (int d = 0; d < 32; ++d) a += w[d] * x[d * 3 + i];
                Pv[(size_t)n * 64 + c * 4 + i] = a;
            } else {
                int idx = s - 64, c = idx / 9, ij = idx % 9;
                float a = 0.f;
                const float* w = WL2 + c * 16;
                const float* x = sxd + ln * 144;
                for (int d = 0; d < 16; ++d) a += w[d] * x[d * 9 + ij];
                Pd[(size_t)n * 192 + c * 12 + ij] = a;
            }
        }
        return;
    }
    b -= NPB;
    int i = b * 256 + tid;
    if (i < E) {
        atomicAdd(&cnt_s[src[i]], 1);
        atomicAdd(&cnt_d[dst[i]], 1);
    }
}

// --------------------------------------------------------------- CSR ----
__global__ void scan_rows2(const int* __restrict__ cnt_s, int* __restrict__ rs_s,
                           const int* __restrict__ cnt_d, int* __restrict__ rs_d, int N) {
    const int* cnt = blockIdx.x ? cnt_d : cnt_s;
    int* rowstart = blockIdx.x ? rs_d : rs_s;
    __shared__ int ps[256];
    int t = threadIdx.x;
    int chunk = (N + 255) / 256;
    int base = t * chunk;
    int s = 0;
    for (int i = 0; i < chunk; ++i) { int idx = base + i; if (idx < N) s += cnt[idx]; }
    ps[t] = s;
    __syncthreads();
    for (int off = 1; off < 256; off <<= 1) {
        int v = (t >= off) ? ps[t - off] : 0;
        __syncthreads();
        ps[t] += v;
        __syncthreads();
    }
    int run = (t > 0) ? ps[t - 1] : 0;
    for (int i = 0; i < chunk; ++i) {
        int idx = base + i;
        if (idx < N) { rowstart[idx] = run; run += cnt[idx]; }
    }
    if (t == 255) rowstart[N] = run;
}

__global__ void fill_slot(const int* __restrict__ src, const int* __restrict__ dst,
                          const int* __restrict__ rs_s, const int* __restrict__ rs_d,
                          int* __restrict__ cur_s, int* __restrict__ cur_d,
                          int* __restrict__ slot, int* __restrict__ eperm, int E) {
    int i = blockIdx.x * 256 + threadIdx.x;
    if (i < E) {
        slot[i] = rs_s[src[i]] + atomicAdd(&cur_s[src[i]], 1);
        int p = rs_d[dst[i]] + atomicAdd(&cur_d[dst[i]], 1);
        eperm[p] = i;
    }
}

// ---------------------------------------------------------- edge_mfma ----
// BARRIER-FREE: each wave owns 4 edges end-to-end in a private 8080B LDS
// slice (4 waves x 8080 = 32320B -> 5 blocks/CU). Per-wave M=4/12/36 MFMA
// tiles read garbage rows beyond own data (ignored; all reads verified
// within the wave slice). Same-wave LDS ordering via lgkmcnt, no syncs.
__global__ __launch_bounds__(256, 5) void edge_mfma(
    const float* __restrict__ r_ij,
    const float* __restrict__ Pa, const float* __restrict__ Pv, const float* __restrict__ Pd,
    const float* __restrict__ Wenc, const float* __restrict__ benc,
    const bf16* __restrict__ Wa, const bf16* __restrict__ Wv, const bf16* __restrict__ Wd,
    const bf16* __restrict__ Wb1, const bf16* __restrict__ Wb2,
    const bf16* __restrict__ Wb3, const bf16* __restrict__ Wbdir,
    const float* __restrict__ b1, const float* __restrict__ b2, const float* __restrict__ b3,
    const int* __restrict__ slot, const int* __restrict__ dst,
    const int* __restrict__ eperm,
    short* __restrict__ psi, int E, int nwg)
{
    __shared__ __align__(16) char smem[32320];
    const int tid = threadIdx.x;
    const int wid = tid >> 6, lane = tid & 63;
    short* wb = (short*)(smem + wid * 8080);
    short* SYA   = wb;                          // [4][48]   bytes [0,384)
    short* SYV   = wb + 192;                    // [12][80]  [384,2304)
    short* SYD   = wb + 1152;                   // [36][80]  [2304,8064)
    int*   SSLOT = (int*)((char*)wb + 8064);    // [4]       [8064,8080)
    // aliases (written only after the tensor GEMM reads, same wave):
    short* SPSIA = wb + 192;                    // [4][72]
    short* SH1   = wb + 480;                    // [4][136]
    short* SH2   = wb + 1024;                   // [4][136]
    short* SPSI  = wb + 2816;                   // [4][304]  [5632,8064)

    // bijective XCD swizzle over 16-edge tiles
    int orig = blockIdx.x;
    int qn = nwg >> 3, rn = nwg & 7;
    int xcd = orig & 7, tidx = orig >> 3;
    int tile = (xcd < rn) ? (xcd * (qn + 1) + tidx) : (rn * (qn + 1) + (xcd - rn) * qn + tidx);
    const int ebase = tile * 16 + wid * 4;      // this wave's 4 edges
    const bf16x8 z8 = {};

    // ---- phase 1: y-build. lane = (local edge le, channel c)
    {
        const int le = lane >> 4, c = lane & 15;
        if (ebase + le < E) {
            const int e = eperm[ebase + le];
            const int j = dst[e];
            if (c == 0) SSLOT[le] = slot[e];
            float vx = 7.f * r_ij[e * 3 + 0];
            float vy = 7.f * r_ij[e * 3 + 1];
            float vz = 7.f * r_ij[e * 3 + 2];
            float nn = sqrtf(vx * vx + vy * vy + vz * vz);
            float ex = __expf(-2.f * nn);
            float th = (1.f - ex) * __builtin_amdgcn_rcpf(1.f + ex);
            float sc = th * __builtin_amdgcn_rcpf(nn + 1e-12f);
            float rr[3] = {vx * sc, vy * sc, vz * sc};
            float x8 = nn * (8.f / 7.f);
            float rad = benc[c];
            #pragma unroll
            for (int m = 0; m < 8; ++m) {
                float tt = x8 - (float)m;
                rad += __expf(-0.5f * tt * tt) * Wenc[c * 8 + m];
            }
            float xa = Pa[j * 16 + c];
            f32x4 pv4 = *(const f32x4*)(Pv + (size_t)j * 64 + c * 4);
            f32x4 pd0 = *(const f32x4*)(Pd + (size_t)j * 192 + c * 12);
            f32x4 pd1 = *(const f32x4*)(Pd + (size_t)j * 192 + c * 12 + 4);
            f32x4 pd2 = *(const f32x4*)(Pd + (size_t)j * 192 + c * 12 + 8);
            float xv[3] = {pv4[0], pv4[1], pv4[2]};
            float xd[9] = {pd0[0], pd0[1], pd0[2], pd0[3], pd1[0], pd1[1], pd1[2], pd1[3], pd2[0]};
            float dotv = xv[0] * rr[0] + xv[1] * rr[1] + xv[2] * rr[2];
            float mv[3];
            #pragma unroll
            for (int i = 0; i < 3; ++i)
                mv[i] = xd[i * 3] * rr[0] + xd[i * 3 + 1] * rr[1] + xd[i * 3 + 2] * rr[2];
            float quad = mv[0] * rr[0] + mv[1] * rr[1] + mv[2] * rr[2];
            st_bf16(&SYA[le * 48 + c],      xa * rad);
            st_bf16(&SYA[le * 48 + 16 + c], rad * dotv);
            st_bf16(&SYA[le * 48 + 32 + c], rad * quad);
            #pragma unroll
            for (int i = 0; i < 3; ++i) {
                int row = (le * 3 + i) * 80;
                int i1 = (i + 1) % 3, i2 = (i + 2) % 3;
                st_bf16(&SYV[row + c],      xa * rad * rr[i]);
                st_bf16(&SYV[row + 16 + c], rad * xv[i]);
                st_bf16(&SYV[row + 32 + c], rad * dotv * rr[i]);
                st_bf16(&SYV[row + 48 + c], rad * mv[i]);
                st_bf16(&SYV[row + 64 + c], rad * (xv[i1] * rr[i2] - xv[i2] * rr[i1]));
            }
            #pragma unroll
            for (int i = 0; i < 3; ++i) {
                int i1 = (i + 1) % 3, i2 = (i + 2) % 3;
                #pragma unroll
                for (int jj = 0; jj < 3; ++jj) {
                    int row = (le * 9 + i * 3 + jj) * 80;
                    st_bf16(&SYD[row + c],      xa * rad * rr[i] * rr[jj]);
                    st_bf16(&SYD[row + 16 + c], rad * xd[i * 3 + jj]);
                    st_bf16(&SYD[row + 32 + c], rad * xv[i] * rr[jj]);
                    st_bf16(&SYD[row + 48 + c], rad * mv[i] * rr[jj]);
                    st_bf16(&SYD[row + 64 + c], rad * (xd[i1 * 3 + jj] * rr[i2] - xd[i2 * 3 + jj] * rr[i1]));
                }
            }
        }
    }
    // (no barrier — same-wave LDS deps ordered by lgkmcnt)

    const int q16 = lane >> 4, r16 = lane & 15;

    // ---- phase 2: per-wave tensor GEMMs (all reads before any alias write)
    f32x4 da[4] = {};
    f32x4 dv[2] = {};
    f32x4 dd[3] = {};
    {   // psi_a: M=4 (rows 0-3 real), N=64, K=48
        bf16x8 af0 = *(const bf16x8*)&SYA[r16 * 48 + q16 * 8];
        bf16x8 af1 = z8;
        if (q16 < 2) af1 = *(const bf16x8*)&SYA[r16 * 48 + 32 + q16 * 8];
        #pragma unroll
        for (int n = 0; n < 4; ++n) {
            bf16x8 bf0 = *(const bf16x8*)((const short*)Wa + (n * 16 + r16) * 64 + q16 * 8);
            bf16x8 bf1 = *(const bf16x8*)((const short*)Wa + (n * 16 + r16) * 64 + 32 + q16 * 8);
            da[n] = __builtin_amdgcn_mfma_f32_16x16x32_bf16(af0, bf0, da[n], 0, 0, 0);
            da[n] = __builtin_amdgcn_mfma_f32_16x16x32_bf16(af1, bf1, da[n], 0, 0, 0);
        }
    }
    {   // psi_v: M=12 (rows 0-11 real), N=32, K=80
        #pragma unroll
        for (int ks = 0; ks < 3; ++ks) {
            bf16x8 av;
            if (ks < 2) av = *(const bf16x8*)&SYV[r16 * 80 + ks * 32 + q16 * 8];
            else {
                av = z8;
                if (q16 < 2) av = *(const bf16x8*)&SYV[r16 * 80 + 64 + q16 * 8];
            }
            #pragma unroll
            for (int n = 0; n < 2; ++n) {
                bf16x8 bv = *(const bf16x8*)((const short*)Wv + (n * 16 + r16) * 96 + ks * 32 + q16 * 8);
                dv[n] = __builtin_amdgcn_mfma_f32_16x16x32_bf16(av, bv, dv[n], 0, 0, 0);
            }
        }
    }
    {   // psi_d: M=36, N=16, K=80; tiles at rows {0,16,20} (backshifted last)
        const int mrow[3] = {0, 16, 20};
        #pragma unroll
        for (int ks = 0; ks < 3; ++ks) {
            bf16x8 bf = *(const bf16x8*)((const short*)Wd + r16 * 96 + ks * 32 + q16 * 8);
            #pragma unroll
            for (int mi = 0; mi < 3; ++mi) {
                bf16x8 af;
                if (ks < 2) af = *(const bf16x8*)&SYD[(mrow[mi] + r16) * 80 + ks * 32 + q16 * 8];
                else {
                    af = z8;
                    if (q16 < 2) af = *(const bf16x8*)&SYD[(mrow[mi] + r16) * 80 + 64 + q16 * 8];
                }
                dd[mi] = __builtin_amdgcn_mfma_f32_16x16x32_bf16(af, bf, dd[mi], 0, 0, 0);
            }
        }
    }

    // ---- epilogues into aliased scratch (same wave, after all GEMM reads)
    if (q16 == 0) {
        #pragma unroll
        for (int n = 0; n < 4; ++n)
            #pragma unroll
            for (int jj = 0; jj < 4; ++jj)
                st_bf16(&SPSIA[jj * 72 + n * 16 + r16], da[n][jj]);
    }
    if (q16 < 3) {
        #pragma unroll
        for (int n = 0; n < 2; ++n)
            #pragma unroll
            for (int jj = 0; jj < 4; ++jj) {
                int row = q16 * 4 + jj;
                int el = row / 3, i = row % 3;
                st_bf16(&SPSI[el * 304 + 64 + (n * 16 + r16) * 3 + i], dv[n][jj]);
            }
    }
    {
        const int mrow[3] = {0, 16, 20};
        #pragma unroll
        for (int mi = 0; mi < 3; ++mi) {
            if (mi == 2 && q16 != 3) continue;
            #pragma unroll
            for (int jj = 0; jj < 4; ++jj) {
                int grow = mrow[mi] + q16 * 4 + jj;
                if (mi == 2) grow = 32 + jj;       // q16==3 only
                int el = grow / 9, ij = grow % 9;
                st_bf16(&SPSI[el * 304 + 160 + r16 * 9 + ij], dd[mi][jj]);
            }
        }
    }

    // ---- phase 3: fused MLP, M=4
    {   // L1: h1 = lrelu(psia @ W1^T + b1), K=64, N=128
        f32x4 h1a[8] = {};
        #pragma unroll
        for (int ks = 0; ks < 2; ++ks) {
            bf16x8 af = *(const bf16x8*)&SPSIA[r16 * 72 + ks * 32 + q16 * 8];
            #pragma unroll
            for (int n = 0; n < 8; ++n) {
                int col = n * 16 + r16;
                bf16x8 bf = *(const bf16x8*)((const short*)Wb1 + col * 64 + ks * 32 + q16 * 8);
                h1a[n] = __builtin_amdgcn_mfma_f32_16x16x32_bf16(af, bf, h1a[n], 0, 0, 0);
            }
        }
        if (q16 == 0) {
            #pragma unroll
            for (int n = 0; n < 8; ++n) {
                int col = n * 16 + r16;
                float bias = b1[col];
                #pragma unroll
                for (int jj = 0; jj < 4; ++jj) {
                    float v = h1a[n][jj] + bias;
                    v = v >= 0.f ? v : 0.1f * v;
                    st_bf16(&SH1[jj * 136 + col], v);
                }
            }
        }
    }
    {   // L2: h2 = lrelu(h1 @ W2^T + b2), K=128, N=128
        f32x4 h2a[8] = {};
        #pragma unroll
        for (int ks = 0; ks < 4; ++ks) {
            bf16x8 af = *(const bf16x8*)&SH1[r16 * 136 + ks * 32 + q16 * 8];
            #pragma unroll
            for (int n = 0; n < 8; ++n) {
                int col = n * 16 + r16;
                bf16x8 bf = *(const bf16x8*)((const short*)Wb2 + col * 128 + ks * 32 + q16 * 8);
                h2a[n] = __builtin_amdgcn_mfma_f32_16x16x32_bf16(af, bf, h2a[n], 0, 0, 0);
            }
        }
        if (q16 == 0) {
            #pragma unroll
            for (int n = 0; n < 8; ++n) {
                int col = n * 16 + r16;
                float bias = b2[col];
                #pragma unroll
                for (int jj = 0; jj < 4; ++jj) {
                    float v = h2a[n][jj] + bias;
                    v = v >= 0.f ? v : 0.1f * v;
                    st_bf16(&SH2[jj * 136 + col], v);
                }
            }
        }
    }
    {   // L3: out = psia + psia@Wdir^T + h2@W3^T + b3, N=64
        f32x4 o3[4] = {};
        #pragma unroll
        for (int ks = 0; ks < 4; ++ks) {
            bf16x8 af = *(const bf16x8*)&SH2[r16 * 136 + ks * 32 + q16 * 8];
            #pragma unroll
            for (int n = 0; n < 4; ++n) {
                int col = n * 16 + r16;
                bf16x8 bf = *(const bf16x8*)((const short*)Wb3 + col * 128 + ks * 32 + q16 * 8);
                o3[n] = __builtin_amdgcn_mfma_f32_16x16x32_bf16(af, bf, o3[n], 0, 0, 0);
            }
        }
        #pragma unroll
        for (int ks = 0; ks < 2; ++ks) {
            bf16x8 af = *(const bf16x8*)&SPSIA[r16 * 72 + ks * 32 + q16 * 8];
            #pragma unroll
            for (int n = 0; n < 4; ++n) {
                int col = n * 16 + r16;
                bf16x8 bf = *(const bf16x8*)((const short*)Wbdir + col * 64 + ks * 32 + q16 * 8);
                o3[n] = __builtin_amdgcn_mfma_f32_16x16x32_bf16(af, bf, o3[n], 0, 0, 0);
            }
        }
        if (q16 == 0) {
            #pragma unroll
            for (int n = 0; n < 4; ++n) {
                int col = n * 16 + r16;
                float bias = b3[col];
                #pragma unroll
                for (int jj = 0; jj < 4; ++jj) {
                    float v = o3[n][jj] + bias + bb2f(SPSIA[jj * 72 + col]);
                    st_bf16(&SPSI[jj * 304 + col], v);
                }
            }
        }
    }

    // ---- coalesced psi-row store at CSR slot (wave-private)
    {
        const uint32_t* S32 = (const uint32_t*)SPSI;
        uint32_t* P32 = (uint32_t*)psi;
        for (int idx = lane; idx < 608; idx += 64) {
            int le = idx / 152, k = idx - le * 152;
            if (ebase + le < E)
                P32[(size_t)SSLOT[le] * 152 + k] = S32[le * 152 + k];
        }
    }
}

// -------------------------------------------------------------- gather ----
__global__ __launch_bounds__(128) void gather(
    const short* __restrict__ psi, const int* __restrict__ rowstart,
    float* __restrict__ out, int N) {
    int n = blockIdx.x, t = threadIdx.x;
    if (t >= 76) return;
    int s0 = rowstart[n], s1 = rowstart[n + 1];
    float a0 = 0.f, a1 = 0.f, a2 = 0.f, a3 = 0.f;
    for (int s = s0; s < s1; ++s) {
        const uint32_t* p = (const uint32_t*)(psi + (size_t)s * 304) + 2 * t;
        uint32_t u0 = p[0], u1 = p[1];
        a0 += __uint_as_float(u0 << 16);
        a1 += __uint_as_float(u0 & 0xffff0000u);
        a2 += __uint_as_float(u1 << 16);
        a3 += __uint_as_float(u1 & 0xffff0000u);
    }
    int f = 4 * t;
    f32x4 v = {0.1f * a0, 0.1f * a1, 0.1f * a2, 0.1f * a3};
    if (f < 64)       *(f32x4*)&out[(size_t)n * 64 + f] = v;
    else if (f < 160) *(f32x4*)&out[(size_t)N * 64 + (size_t)n * 96 + (f - 64)] = v;
    else              *(f32x4*)&out[(size_t)N * 160 + (size_t)n * 144 + (f - 160)] = v;
}

// -------------------------------------------------------------- launch ----
extern "C" void kernel_launch(void* const* d_in, const int* in_sizes, int n_in,
                              void* d_out, int out_size, void* d_ws, size_t ws_size,
                              hipStream_t stream) {
    const float* r_ij = (const float*)d_in[0];
    const float* x_a  = (const float*)d_in[1];
    const float* x_v  = (const float*)d_in[2];
    const float* x_d  = (const float*)d_in[3];
    const float* W_L0 = (const float*)d_in[4];
    const float* W_L1 = (const float*)d_in[5];
    const float* W_L2 = (const float*)d_in[6];
    const float* W000 = (const float*)d_in[7];
    const float* W110 = (const float*)d_in[8];
    const float* W220 = (const float*)d_in[9];
    const float* W011 = (const float*)d_in[10];
    const float* W101 = (const float*)d_in[11];
    const float* W121 = (const float*)d_in[12];
    const float* W211 = (const float*)d_in[13];
    const float* W022 = (const float*)d_in[14];
    const float* W202 = (const float*)d_in[15];
    const float* W112 = (const float*)d_in[16];
    const float* W222 = (const float*)d_in[17];
    const float* W111 = (const float*)d_in[18];
    const float* W212 = (const float*)d_in[19];
    const float* Wenc = (const float*)d_in[20];
    const float* benc = (const float*)d_in[21];
    const float* Wdir = (const float*)d_in[22];
    const float* W1   = (const float*)d_in[23];
    const float* b1   = (const float*)d_in[24];
    const float* W2   = (const float*)d_in[25];
    const float* b2   = (const float*)d_in[26];
    const float* W3   = (const float*)d_in[27];
    const float* b3   = (const float*)d_in[28];
    const int* src    = (const int*)d_in[29];
    const int* dst    = (const int*)d_in[30];

    const int E = in_sizes[29];
    const int N = in_sizes[1] / 64;

    // ws layout
    float* Pa     = (float*)d_ws;                    // N*16
    float* Pv     = Pa + (size_t)N * 16;             // N*64
    float* Pd     = Pv + (size_t)N * 64;             // N*192
    bf16*  Wb     = (bf16*)(Pd + (size_t)N * 192);   // 45568 bf16
    int*   cnt_s  = (int*)(Wb + 45568);              // N
    int*   cur_s  = cnt_s + N;                       // N
    int*   cnt_d  = cur_s + N;                       // N
    int*   cur_d  = cnt_d + N;                       // N
    int*   rs_s   = cur_d + N;                       // N+1
    int*   rs_d   = rs_s + N + 1;                    // N+1
    int*   slot   = rs_d + N + 1;                    // E
    int*   eperm  = slot + E;                        // E
    short* psi    = (short*)(eperm + E);             // E*304 bf16

    const bf16* Wa_p    = Wb;
    const bf16* Wv_p    = Wb + 4096;
    const bf16* Wd_p    = Wb + 7168;
    const bf16* Wb1_p   = Wb + 8704;
    const bf16* Wb2_p   = Wb + 16896;
    const bf16* Wb3_p   = Wb + 33280;
    const bf16* Wbdir_p = Wb + 41472;

    const int NPB = (N + 3) / 4;
    const int HB  = (E + 255) / 256;
    const int nwg = (E + 15) / 16;

    hipMemsetAsync(cnt_s, 0, (size_t)4 * N * sizeof(int), stream);
    prep_all<<<178 + NPB + HB, 256, 0, stream>>>(
        W000, W110, W220, W011, W101, W121, W211, W111,
        W022, W202, W112, W222, W212, W1, W2, W3, Wdir, Wb,
        x_a, x_v, x_d, W_L0, W_L1, W_L2, Pa, Pv, Pd, N, NPB,
        src, dst, cnt_s, cnt_d, E);
    scan_rows2<<<2, 256, 0, stream>>>(cnt_s, rs_s, cnt_d, rs_d, N);
    fill_slot<<<HB, 256, 0, stream>>>(src, dst, rs_s, rs_d, cur_s, cur_d, slot, eperm, E);
    edge_mfma<<<nwg, 256, 0, stream>>>(
        r_ij, Pa, Pv, Pd, Wenc, benc,
        Wa_p, Wv_p, Wd_p, Wb1_p, Wb2_p, Wb3_p, Wbdir_p,
        b1, b2, b3, slot, dst, eperm, psi, E, nwg);
    gather<<<N, 128, 0, stream>>>(psi, rs_s, (float*)d_out, N);
}

// Round 11
// 436.022 us; speedup vs baseline: 1.1762x; 1.1762x over previous
//
#include <hip/hip_runtime.h>
#include <hip/hip_bf16.h>

typedef __hip_bfloat16 bf16;
typedef __attribute__((ext_vector_type(8))) short bf16x8;
typedef __attribute__((ext_vector_type(4))) float f32x4;

__device__ __forceinline__ void st_bf16(short* p, float v) {
    uint32_t u = __float_as_uint(v) + 0x8000u;
    *p = (short)(u >> 16);
}
__device__ __forceinline__ float bb2f(short s) {
    uint32_t u = ((uint32_t)(uint16_t)s) << 16;
    return __uint_as_float(u);
}

// ------------------------------------------------------------- prep_all ----
__global__ __launch_bounds__(256) void prep_all(
    const float* __restrict__ W000, const float* __restrict__ W110, const float* __restrict__ W220,
    const float* __restrict__ W011, const float* __restrict__ W101, const float* __restrict__ W121,
    const float* __restrict__ W211, const float* __restrict__ W111,
    const float* __restrict__ W022, const float* __restrict__ W202, const float* __restrict__ W112,
    const float* __restrict__ W222, const float* __restrict__ W212,
    const float* __restrict__ W1, const float* __restrict__ W2, const float* __restrict__ W3,
    const float* __restrict__ Wdir, bf16* __restrict__ wout,
    const float* __restrict__ xa, const float* __restrict__ xv, const float* __restrict__ xd,
    const float* __restrict__ WL0, const float* __restrict__ WL1, const float* __restrict__ WL2,
    float* __restrict__ Pa, float* __restrict__ Pv, float* __restrict__ Pd, int N, int NPB,
    const int* __restrict__ src, const int* __restrict__ dst,
    int* __restrict__ cnt_s, int* __restrict__ cnt_d, int E)
{
    int b = blockIdx.x;
    const int tid = threadIdx.x;
    if (b < 178) {
        int i = b * 256 + tid;
        if (i >= 45568) return;
        float v = 0.f;
        if (i < 4096) {
            int o = i >> 6, k = i & 63;
            if (k < 48) {
                int t = k >> 4, c = k & 15;
                const float* W = (t == 0) ? W000 : (t == 1) ? W110 : W220;
                v = W[o * 16 + c];
            }
        } else if (i < 7168) {
            int r = i - 4096, ch = r / 96, k = r % 96;
            if (k < 80) {
                int t = k >> 4, c = k & 15;
                const float* W = (t == 0) ? W011 : (t == 1) ? W101 : (t == 2) ? W121 : (t == 3) ? W211 : W111;
                v = W[ch * 16 + c];
            }
        } else if (i < 8704) {
            int r = i - 7168, ch = r / 96, k = r % 96;
            if (k < 80) {
                int t = k >> 4, c = k & 15;
                const float* W = (t == 0) ? W022 : (t == 1) ? W202 : (t == 2) ? W112 : (t == 3) ? W222 : W212;
                v = W[ch * 16 + c];
            }
        } else if (i < 16896) v = W1[i - 8704];
        else if (i < 33280) v = W2[i - 16896];
        else if (i < 41472) v = W3[i - 33280];
        else v = Wdir[i - 41472];
        wout[i] = __float2bfloat16(v);
        return;
    }
    b -= 178;
    if (b < NPB) {
        __shared__ float sxa[256], sxv[384], sxd[576];
        const int n0 = b * 4;
        if (n0 + tid / 64 < N) sxa[tid] = xa[(size_t)n0 * 64 + tid];
        for (int i = tid; i < 384; i += 256) if (n0 + i / 96 < N)  sxv[i] = xv[(size_t)n0 * 96 + i];
        for (int i = tid; i < 576; i += 256) if (n0 + i / 144 < N) sxd[i] = xd[(size_t)n0 * 144 + i];
        __syncthreads();
        for (int o = tid; o < 832; o += 256) {
            int ln = o / 208, s = o % 208;
            int n = n0 + ln;
            if (n >= N) continue;
            if (s < 16) {
                float a = 0.f;
                const float* w = WL0 + s * 64;
                const float* x = sxa + ln * 64;
                for (int d = 0; d < 64; ++d) a += w[d] * x[d];
                Pa[(size_t)n * 16 + s] = a;
            } else if (s < 64) {
                int idx = s - 16, c = idx / 3, i = idx % 3;
                float a = 0.f;
                const float* w = WL1 + c * 32;
                const float* x = sxv + ln * 96;
                for (int d = 0; d < 32; ++d) a += w[d] * x[d * 3 + i];
                Pv[(size_t)n * 64 + c * 4 + i] = a;
            } else {
                int idx = s - 64, c = idx / 9, ij = idx % 9;
                float a = 0.f;
                const float* w = WL2 + c * 16;
                const float* x = sxd + ln * 144;
                for (int d = 0; d < 16; ++d) a += w[d] * x[d * 9 + ij];
                Pd[(size_t)n * 192 + c * 12 + ij] = a;
            }
        }
        return;
    }
    b -= NPB;
    int i = b * 256 + tid;
    if (i < E) {
        atomicAdd(&cnt_s[src[i]], 1);
        atomicAdd(&cnt_d[dst[i]], 1);
    }
}

// --------------------------------------------------------------- CSR ----
__global__ void scan_rows2(const int* __restrict__ cnt_s, int* __restrict__ rs_s,
                           const int* __restrict__ cnt_d, int* __restrict__ rs_d, int N) {
    const int* cnt = blockIdx.x ? cnt_d : cnt_s;
    int* rowstart = blockIdx.x ? rs_d : rs_s;
    __shared__ int ps[256];
    int t = threadIdx.x;
    int chunk = (N + 255) / 256;
    int base = t * chunk;
    int s = 0;
    for (int i = 0; i < chunk; ++i) { int idx = base + i; if (idx < N) s += cnt[idx]; }
    ps[t] = s;
    __syncthreads();
    for (int off = 1; off < 256; off <<= 1) {
        int v = (t >= off) ? ps[t - off] : 0;
        __syncthreads();
        ps[t] += v;
        __syncthreads();
    }
    int run = (t > 0) ? ps[t - 1] : 0;
    for (int i = 0; i < chunk; ++i) {
        int idx = base + i;
        if (idx < N) { rowstart[idx] = run; run += cnt[idx]; }
    }
    if (t == 255) rowstart[N] = run;
}

__global__ void fill_slot(const int* __restrict__ src, const int* __restrict__ dst,
                          const int* __restrict__ rs_s, const int* __restrict__ rs_d,
                          int* __restrict__ cur_s, int* __restrict__ cur_d,
                          int* __restrict__ slot, int* __restrict__ eperm, int E) {
    int i = blockIdx.x * 256 + threadIdx.x;
    if (i < E) {
        slot[i] = rs_s[src[i]] + atomicAdd(&cur_s[src[i]], 1);
        int p = rs_d[dst[i]] + atomicAdd(&cur_d[dst[i]], 1);
        eperm[p] = i;
    }
}

// ---------------------------------------------------------- edge_mfma ----
// Round-9 lockstep 16-edge tile structure + PERSISTENT blocks, each owning a
// contiguous chunk of dst-sorted tiles, with full register prefetch of the
// next tile's inputs (T14 issue-early/consume-late) so the chained
// eperm->dst->P gather latency hides under the current tile's MFMA phases.
__global__ __launch_bounds__(256, 5) void edge_mfma(
    const float* __restrict__ r_ij,
    const float* __restrict__ Pa, const float* __restrict__ Pv, const float* __restrict__ Pd,
    const float* __restrict__ Wenc, const float* __restrict__ benc,
    const bf16* __restrict__ Wa, const bf16* __restrict__ Wv, const bf16* __restrict__ Wd,
    const bf16* __restrict__ Wb1, const bf16* __restrict__ Wb2,
    const bf16* __restrict__ Wb3, const bf16* __restrict__ Wbdir,
    const float* __restrict__ b1, const float* __restrict__ b2, const float* __restrict__ b3,
    const int* __restrict__ slot, const int* __restrict__ dst,
    const int* __restrict__ eperm,
    short* __restrict__ psi, int E, int TT, int chunk)
{
    __shared__ __align__(16) char smem[32320];
    short* SYA   = (short*)smem;            // [16][48]
    short* SYV   = (short*)(smem + 1536);   // [48][80]
    short* SYD   = (short*)(smem + 9216);   // [144][80]
    int*   SSLOT = (int*)(smem + 32256);    // [16]
    // phase-3 aliases (valid after b2)
    short* SPSIA = (short*)(smem + 1536);   // [16][72]
    short* SH1   = (short*)(smem + 3840);   // [16][136]
    short* SH2   = (short*)(smem + 8192);   // [16][136]
    short* SPSI  = (short*)(smem + 12544);  // [16][304]

    const int tid = threadIdx.x;
    const int wid = tid >> 6, lane = tid & 63;
    const int q16 = lane >> 4, r16 = lane & 15;
    const int le = tid >> 4, c = tid & 15;
    const bf16x8 z8 = {};

    const int tstart = blockIdx.x * chunk;
    const int tend = min(TT, tstart + chunk);
    if (tstart >= tend) return;

    // ---- prefetch registers (next tile's per-thread inputs)
    bool nvalid = false;
    int nsl = 0;
    float nr0 = 0.f, nr1 = 0.f, nr2 = 0.f, npa = 0.f;
    f32x4 npv = {}, npd0 = {}, npd1 = {}, npd2 = {};

    #define DO_PREFETCH(TILE)                                              \
        {                                                                   \
            int eb = (TILE) * 16 + le;                                      \
            nvalid = (eb < E);                                              \
            if (nvalid) {                                                   \
                int e_ = eperm[eb];                                         \
                int j_ = dst[e_];                                           \
                nsl = slot[e_];                                             \
                nr0 = r_ij[e_ * 3 + 0];                                     \
                nr1 = r_ij[e_ * 3 + 1];                                     \
                nr2 = r_ij[e_ * 3 + 2];                                     \
                npa = Pa[j_ * 16 + c];                                      \
                npv = *(const f32x4*)(Pv + (size_t)j_ * 64 + c * 4);        \
                npd0 = *(const f32x4*)(Pd + (size_t)j_ * 192 + c * 12);     \
                npd1 = *(const f32x4*)(Pd + (size_t)j_ * 192 + c * 12 + 4); \
                npd2 = *(const f32x4*)(Pd + (size_t)j_ * 192 + c * 12 + 8); \
            }                                                               \
        }

    DO_PREFETCH(tstart);

    for (int t = tstart; t < tend; ++t) {
        const int e0 = t * 16;
        // ---- consume prefetched regs into locals
        const bool valid = nvalid;
        const int sl = nsl;
        const float cr0 = nr0, cr1 = nr1, cr2 = nr2, cpa = npa;
        const f32x4 cpv = npv, cpd0 = npd0, cpd1 = npd1, cpd2 = npd2;
        // ---- issue next tile's prefetch (resolves under this tile's phases)
        if (t + 1 < tend) DO_PREFETCH(t + 1);

        // ---- phase 1: y-build from locals
        if (valid) {
            if (c == 0) SSLOT[le] = sl;
            float vx = 7.f * cr0, vy = 7.f * cr1, vz = 7.f * cr2;
            float nn = sqrtf(vx * vx + vy * vy + vz * vz);
            float ex = __expf(-2.f * nn);
            float th = (1.f - ex) * __builtin_amdgcn_rcpf(1.f + ex);
            float sc = th * __builtin_amdgcn_rcpf(nn + 1e-12f);
            float rr[3] = {vx * sc, vy * sc, vz * sc};
            float x8 = nn * (8.f / 7.f);
            float rad = benc[c];
            #pragma unroll
            for (int m = 0; m < 8; ++m) {
                float tt = x8 - (float)m;
                rad += __expf(-0.5f * tt * tt) * Wenc[c * 8 + m];
            }
            float xa = cpa;
            float xv[3] = {cpv[0], cpv[1], cpv[2]};
            float xd[9] = {cpd0[0], cpd0[1], cpd0[2], cpd0[3],
                           cpd1[0], cpd1[1], cpd1[2], cpd1[3], cpd2[0]};
            float dotv = xv[0] * rr[0] + xv[1] * rr[1] + xv[2] * rr[2];
            float mv[3];
            #pragma unroll
            for (int i = 0; i < 3; ++i)
                mv[i] = xd[i * 3] * rr[0] + xd[i * 3 + 1] * rr[1] + xd[i * 3 + 2] * rr[2];
            float quad = mv[0] * rr[0] + mv[1] * rr[1] + mv[2] * rr[2];
            st_bf16(&SYA[le * 48 + c],      xa * rad);
            st_bf16(&SYA[le * 48 + 16 + c], rad * dotv);
            st_bf16(&SYA[le * 48 + 32 + c], rad * quad);
            #pragma unroll
            for (int i = 0; i < 3; ++i) {
                int row = (le * 3 + i) * 80;
                int i1 = (i + 1) % 3, i2 = (i + 2) % 3;
                st_bf16(&SYV[row + c],      xa * rad * rr[i]);
                st_bf16(&SYV[row + 16 + c], rad * xv[i]);
                st_bf16(&SYV[row + 32 + c], rad * dotv * rr[i]);
                st_bf16(&SYV[row + 48 + c], rad * mv[i]);
                st_bf16(&SYV[row + 64 + c], rad * (xv[i1] * rr[i2] - xv[i2] * rr[i1]));
            }
            #pragma unroll
            for (int i = 0; i < 3; ++i) {
                int i1 = (i + 1) % 3, i2 = (i + 2) % 3;
                #pragma unroll
                for (int jj = 0; jj < 3; ++jj) {
                    int row = (le * 9 + i * 3 + jj) * 80;
                    st_bf16(&SYD[row + c],      xa * rad * rr[i] * rr[jj]);
                    st_bf16(&SYD[row + 16 + c], rad * xd[i * 3 + jj]);
                    st_bf16(&SYD[row + 32 + c], rad * xv[i] * rr[jj]);
                    st_bf16(&SYD[row + 48 + c], rad * mv[i] * rr[jj]);
                    st_bf16(&SYD[row + 64 + c], rad * (xd[i1 * 3 + jj] * rr[i2] - xd[i2 * 3 + jj] * rr[i1]));
                }
            }
        }
        __syncthreads();   // b1: y ready

        // ---- phase 2: tensor GEMMs (accumulators persist across b2)
        f32x4 da[4] = {};
        f32x4 dv[3][2] = {};
        f32x4 dd[5] = {};
        const int mstart = (wid == 2) ? 0 : 5;
        const int mcnt = (wid == 2) ? 5 : 4;

        if (wid == 0) {
            bf16x8 af0 = *(const bf16x8*)&SYA[r16 * 48 + q16 * 8];
            bf16x8 af1 = z8;
            if (q16 < 2) af1 = *(const bf16x8*)&SYA[r16 * 48 + 32 + q16 * 8];
            #pragma unroll
            for (int n = 0; n < 4; ++n) {
                bf16x8 bf0 = *(const bf16x8*)((const short*)Wa + (n * 16 + r16) * 64 + q16 * 8);
                bf16x8 bf1 = *(const bf16x8*)((const short*)Wa + (n * 16 + r16) * 64 + 32 + q16 * 8);
                da[n] = __builtin_amdgcn_mfma_f32_16x16x32_bf16(af0, bf0, da[n], 0, 0, 0);
                da[n] = __builtin_amdgcn_mfma_f32_16x16x32_bf16(af1, bf1, da[n], 0, 0, 0);
            }
        } else if (wid == 1) {
            #pragma unroll
            for (int ks = 0; ks < 3; ++ks) {
                bf16x8 av[3], bv[2];
                #pragma unroll
                for (int m = 0; m < 3; ++m) {
                    if (ks < 2) av[m] = *(const bf16x8*)&SYV[(m * 16 + r16) * 80 + ks * 32 + q16 * 8];
                    else {
                        av[m] = z8;
                        if (q16 < 2) av[m] = *(const bf16x8*)&SYV[(m * 16 + r16) * 80 + 64 + q16 * 8];
                    }
                }
                #pragma unroll
                for (int n = 0; n < 2; ++n)
                    bv[n] = *(const bf16x8*)((const short*)Wv + (n * 16 + r16) * 96 + ks * 32 + q16 * 8);
                #pragma unroll
                for (int m = 0; m < 3; ++m)
                    #pragma unroll
                    for (int n = 0; n < 2; ++n)
                        dv[m][n] = __builtin_amdgcn_mfma_f32_16x16x32_bf16(av[m], bv[n], dv[m][n], 0, 0, 0);
            }
        } else {
            #pragma unroll
            for (int ks = 0; ks < 3; ++ks) {
                bf16x8 bf = *(const bf16x8*)((const short*)Wd + r16 * 96 + ks * 32 + q16 * 8);
                for (int mi = 0; mi < mcnt; ++mi) {
                    bf16x8 af;
                    if (ks < 2) af = *(const bf16x8*)&SYD[((mstart + mi) * 16 + r16) * 80 + ks * 32 + q16 * 8];
                    else {
                        af = z8;
                        if (q16 < 2) af = *(const bf16x8*)&SYD[((mstart + mi) * 16 + r16) * 80 + 64 + q16 * 8];
                    }
                    dd[mi] = __builtin_amdgcn_mfma_f32_16x16x32_bf16(af, bf, dd[mi], 0, 0, 0);
                }
            }
        }
        __syncthreads();   // b2: y reads done, alias region reusable

        // ---- epilogues into aliased region
        if (wid == 0) {
            #pragma unroll
            for (int n = 0; n < 4; ++n)
                #pragma unroll
                for (int jj = 0; jj < 4; ++jj)
                    st_bf16(&SPSIA[(q16 * 4 + jj) * 72 + n * 16 + r16], da[n][jj]);
        } else if (wid == 1) {
            #pragma unroll
            for (int m = 0; m < 3; ++m)
                #pragma unroll
                for (int n = 0; n < 2; ++n)
                    #pragma unroll
                    for (int jj = 0; jj < 4; ++jj) {
                        int row = m * 16 + q16 * 4 + jj;
                        int el = row / 3, i = row % 3;
                        st_bf16(&SPSI[el * 304 + 64 + (n * 16 + r16) * 3 + i], dv[m][n][jj]);
                    }
        } else {
            for (int mi = 0; mi < mcnt; ++mi)
                #pragma unroll
                for (int jj = 0; jj < 4; ++jj) {
                    int row = (mstart + mi) * 16 + q16 * 4 + jj;
                    int el = row / 9, ij = row % 9;
                    st_bf16(&SPSI[el * 304 + 160 + r16 * 9 + ij], dd[mi][jj]);
                }
        }
        __syncthreads();   // b3: psi_a + psi_v/d staged

        // ---- phase 3: fused MLP
        {
            f32x4 h1a[2] = {};
            #pragma unroll
            for (int ks = 0; ks < 2; ++ks) {
                bf16x8 af = *(const bf16x8*)&SPSIA[r16 * 72 + ks * 32 + q16 * 8];
                #pragma unroll
                for (int n = 0; n < 2; ++n) {
                    int col = wid * 32 + n * 16 + r16;
                    bf16x8 bf = *(const bf16x8*)((const short*)Wb1 + col * 64 + ks * 32 + q16 * 8);
                    h1a[n] = __builtin_amdgcn_mfma_f32_16x16x32_bf16(af, bf, h1a[n], 0, 0, 0);
                }
            }
            #pragma unroll
            for (int n = 0; n < 2; ++n) {
                int col = wid * 32 + n * 16 + r16;
                float bias = b1[col];
                #pragma unroll
                for (int jj = 0; jj < 4; ++jj) {
                    float v = h1a[n][jj] + bias;
                    v = v >= 0.f ? v : 0.1f * v;
                    st_bf16(&SH1[(q16 * 4 + jj) * 136 + col], v);
                }
            }
        }
        __syncthreads();   // b4: h1 ready
        {
            f32x4 h2a[2] = {};
            #pragma unroll
            for (int ks = 0; ks < 4; ++ks) {
                bf16x8 af = *(const bf16x8*)&SH1[r16 * 136 + ks * 32 + q16 * 8];
                #pragma unroll
                for (int n = 0; n < 2; ++n) {
                    int col = wid * 32 + n * 16 + r16;
                    bf16x8 bf = *(const bf16x8*)((const short*)Wb2 + col * 128 + ks * 32 + q16 * 8);
                    h2a[n] = __builtin_amdgcn_mfma_f32_16x16x32_bf16(af, bf, h2a[n], 0, 0, 0);
                }
            }
            #pragma unroll
            for (int n = 0; n < 2; ++n) {
                int col = wid * 32 + n * 16 + r16;
                float bias = b2[col];
                #pragma unroll
                for (int jj = 0; jj < 4; ++jj) {
                    float v = h2a[n][jj] + bias;
                    v = v >= 0.f ? v : 0.1f * v;
                    st_bf16(&SH2[(q16 * 4 + jj) * 136 + col], v);
                }
            }
        }
        __syncthreads();   // b5: h2 ready
        {
            f32x4 o3 = {};
            const int col3 = wid * 16 + r16;
            #pragma unroll
            for (int ks = 0; ks < 4; ++ks) {
                bf16x8 af = *(const bf16x8*)&SH2[r16 * 136 + ks * 32 + q16 * 8];
                bf16x8 bf = *(const bf16x8*)((const short*)Wb3 + col3 * 128 + ks * 32 + q16 * 8);
                o3 = __builtin_amdgcn_mfma_f32_16x16x32_bf16(af, bf, o3, 0, 0, 0);
            }
            #pragma unroll
            for (int ks = 0; ks < 2; ++ks) {
                bf16x8 af = *(const bf16x8*)&SPSIA[r16 * 72 + ks * 32 + q16 * 8];
                bf16x8 bf = *(const bf16x8*)((const short*)Wbdir + col3 * 64 + ks * 32 + q16 * 8);
                o3 = __builtin_amdgcn_mfma_f32_16x16x32_bf16(af, bf, o3, 0, 0, 0);
            }
            float bias = b3[col3];
            #pragma unroll
            for (int jj = 0; jj < 4; ++jj) {
                int row = q16 * 4 + jj;
                float v = o3[jj] + bias + bb2f(SPSIA[row * 72 + col3]);
                st_bf16(&SPSI[row * 304 + col3], v);
            }
        }
        __syncthreads();   // b6: SPSI complete

        // ---- coalesced psi-row store at CSR slot
        {
            const uint32_t* S32 = (const uint32_t*)SPSI;
            uint32_t* P32 = (uint32_t*)psi;
            for (int idx2 = tid; idx2 < 16 * 152; idx2 += 256) {
                int lee = idx2 / 152, k = idx2 - lee * 152;
                if (e0 + lee < E)
                    P32[(size_t)SSLOT[lee] * 152 + k] = S32[lee * 152 + k];
            }
        }
        __syncthreads();   // b7: SPSI/SSLOT reads done before next phase 1
    }
    #undef DO_PREFETCH
}

// -------------------------------------------------------------- gather ----
__global__ __launch_bounds__(128) void gather(
    const short* __restrict__ psi, const int* __restrict__ rowstart,
    float* __restrict__ out, int N) {
    int n = blockIdx.x, t = threadIdx.x;
    if (t >= 76) return;
    int s0 = rowstart[n], s1 = rowstart[n + 1];
    float a0 = 0.f, a1 = 0.f, a2 = 0.f, a3 = 0.f;
    for (int s = s0; s < s1; ++s) {
        const uint32_t* p = (const uint32_t*)(psi + (size_t)s * 304) + 2 * t;
        uint32_t u0 = p[0], u1 = p[1];
        a0 += __uint_as_float(u0 << 16);
        a1 += __uint_as_float(u0 & 0xffff0000u);
        a2 += __uint_as_float(u1 << 16);
        a3 += __uint_as_float(u1 & 0xffff0000u);
    }
    int f = 4 * t;
    f32x4 v = {0.1f * a0, 0.1f * a1, 0.1f * a2, 0.1f * a3};
    if (f < 64)       *(f32x4*)&out[(size_t)n * 64 + f] = v;
    else if (f < 160) *(f32x4*)&out[(size_t)N * 64 + (size_t)n * 96 + (f - 64)] = v;
    else              *(f32x4*)&out[(size_t)N * 160 + (size_t)n * 144 + (f - 160)] = v;
}

// -------------------------------------------------------------- launch ----
extern "C" void kernel_launch(void* const* d_in, const int* in_sizes, int n_in,
                              void* d_out, int out_size, void* d_ws, size_t ws_size,
                              hipStream_t stream) {
    const float* r_ij = (const float*)d_in[0];
    const float* x_a  = (const float*)d_in[1];
    const float* x_v  = (const float*)d_in[2];
    const float* x_d  = (const float*)d_in[3];
    const float* W_L0 = (const float*)d_in[4];
    const float* W_L1 = (const float*)d_in[5];
    const float* W_L2 = (const float*)d_in[6];
    const float* W000 = (const float*)d_in[7];
    const float* W110 = (const float*)d_in[8];
    const float* W220 = (const float*)d_in[9];
    const float* W011 = (const float*)d_in[10];
    const float* W101 = (const float*)d_in[11];
    const float* W121 = (const float*)d_in[12];
    const float* W211 = (const float*)d_in[13];
    const float* W022 = (const float*)d_in[14];
    const float* W202 = (const float*)d_in[15];
    const float* W112 = (const float*)d_in[16];
    const float* W222 = (const float*)d_in[17];
    const float* W111 = (const float*)d_in[18];
    const float* W212 = (const float*)d_in[19];
    const float* Wenc = (const float*)d_in[20];
    const float* benc = (const float*)d_in[21];
    const float* Wdir = (const float*)d_in[22];
    const float* W1   = (const float*)d_in[23];
    const float* b1   = (const float*)d_in[24];
    const float* W2   = (const float*)d_in[25];
    const float* b2   = (const float*)d_in[26];
    const float* W3   = (const float*)d_in[27];
    const float* b3   = (const float*)d_in[28];
    const int* src    = (const int*)d_in[29];
    const int* dst    = (const int*)d_in[30];

    const int E = in_sizes[29];
    const int N = in_sizes[1] / 64;

    // ws layout
    float* Pa     = (float*)d_ws;                    // N*16
    float* Pv     = Pa + (size_t)N * 16;             // N*64
    float* Pd     = Pv + (size_t)N * 64;             // N*192
    bf16*  Wb     = (bf16*)(Pd + (size_t)N * 192);   // 45568 bf16
    int*   cnt_s  = (int*)(Wb + 45568);              // N
    int*   cur_s  = cnt_s + N;                       // N
    int*   cnt_d  = cur_s + N;                       // N
    int*   cur_d  = cnt_d + N;                       // N
    int*   rs_s   = cur_d + N;                       // N+1
    int*   rs_d   = rs_s + N + 1;                    // N+1
    int*   slot   = rs_d + N + 1;                    // E
    int*   eperm  = slot + E;                        // E
    short* psi    = (short*)(eperm + E);             // E*304 bf16

    const bf16* Wa_p    = Wb;
    const bf16* Wv_p    = Wb + 4096;
    const bf16* Wd_p    = Wb + 7168;
    const bf16* Wb1_p   = Wb + 8704;
    const bf16* Wb2_p   = Wb + 16896;
    const bf16* Wb3_p   = Wb + 33280;
    const bf16* Wbdir_p = Wb + 41472;

    const int NPB = (N + 3) / 4;
    const int HB  = (E + 255) / 256;
    const int TT  = (E + 15) / 16;        // total 16-edge tiles
    const int G   = 1280;                 // persistent blocks (5/CU x 256)
    const int chunk = (TT + G - 1) / G;

    hipMemsetAsync(cnt_s, 0, (size_t)4 * N * sizeof(int), stream);
    prep_all<<<178 + NPB + HB, 256, 0, stream>>>(
        W000, W110, W220, W011, W101, W121, W211, W111,
        W022, W202, W112, W222, W212, W1, W2, W3, Wdir, Wb,
        x_a, x_v, x_d, W_L0, W_L1, W_L2, Pa, Pv, Pd, N, NPB,
        src, dst, cnt_s, cnt_d, E);
    scan_rows2<<<2, 256, 0, stream>>>(cnt_s, rs_s, cnt_d, rs_d, N);
    fill_slot<<<HB, 256, 0, stream>>>(src, dst, rs_s, rs_d, cur_s, cur_d, slot, eperm, E);
    edge_mfma<<<G, 256, 0, stream>>>(
        r_ij, Pa, Pv, Pd, Wenc, benc,
        Wa_p, Wv_p, Wd_p, Wb1_p, Wb2_p, Wb3_p, Wbdir_p,
        b1, b2, b3, slot, dst, eperm, psi, E, TT, chunk);
    gather<<<N, 128, 0, stream>>>(psi, rs_s, (float*)d_out, N);
}

// Round 12
// 259.714 us; speedup vs baseline: 1.9746x; 1.6789x over previous
//
#include <hip/hip_runtime.h>
#include <hip/hip_bf16.h>

typedef __hip_bfloat16 bf16;
typedef __attribute__((ext_vector_type(8))) short bf16x8;
typedef __attribute__((ext_vector_type(4))) float f32x4;

__device__ __forceinline__ void st_bf16(short* p, float v) {
    uint32_t u = __float_as_uint(v) + 0x8000u;
    *p = (short)(u >> 16);
}
__device__ __forceinline__ float bb2f(short s) {
    uint32_t u = ((uint32_t)(uint16_t)s) << 16;
    return __uint_as_float(u);
}

// ------------------------------------------------------------- prep_all ----
// blockIdx: [0,178) prep_w (+WencP in block 0) | [178,178+NPB) node_proj |
// rest: histograms of src AND dst
__global__ __launch_bounds__(256) void prep_all(
    const float* __restrict__ W000, const float* __restrict__ W110, const float* __restrict__ W220,
    const float* __restrict__ W011, const float* __restrict__ W101, const float* __restrict__ W121,
    const float* __restrict__ W211, const float* __restrict__ W111,
    const float* __restrict__ W022, const float* __restrict__ W202, const float* __restrict__ W112,
    const float* __restrict__ W222, const float* __restrict__ W212,
    const float* __restrict__ W1, const float* __restrict__ W2, const float* __restrict__ W3,
    const float* __restrict__ Wdir, bf16* __restrict__ wout,
    const float* __restrict__ Wenc, float* __restrict__ WencP,
    const float* __restrict__ xa, const float* __restrict__ xv, const float* __restrict__ xd,
    const float* __restrict__ WL0, const float* __restrict__ WL1, const float* __restrict__ WL2,
    float* __restrict__ Pa, float* __restrict__ Pv, float* __restrict__ Pd, int N, int NPB,
    const int* __restrict__ src, const int* __restrict__ dst,
    int* __restrict__ cnt_s, int* __restrict__ cnt_d, int E)
{
    int b = blockIdx.x;
    const int tid = threadIdx.x;
    if (b < 178) {
        if (b == 0 && tid < 128) {
            // WencP[c][m] = Wenc[c][m] * exp(-0.5 m^2)  (Gaussian constant folded)
            float m = (float)(tid & 7);
            WencP[tid] = Wenc[tid] * __expf(-0.5f * m * m);
        }
        int i = b * 256 + tid;
        if (i >= 45568) return;
        float v = 0.f;
        if (i < 4096) {
            int o = i >> 6, k = i & 63;
            if (k < 48) {
                int t = k >> 4, c = k & 15;
                const float* W = (t == 0) ? W000 : (t == 1) ? W110 : W220;
                v = W[o * 16 + c];
            }
        } else if (i < 7168) {
            int r = i - 4096, ch = r / 96, k = r % 96;
            if (k < 80) {
                int t = k >> 4, c = k & 15;
                const float* W = (t == 0) ? W011 : (t == 1) ? W101 : (t == 2) ? W121 : (t == 3) ? W211 : W111;
                v = W[ch * 16 + c];
            }
        } else if (i < 8704) {
            int r = i - 7168, ch = r / 96, k = r % 96;
            if (k < 80) {
                int t = k >> 4, c = k & 15;
                const float* W = (t == 0) ? W022 : (t == 1) ? W202 : (t == 2) ? W112 : (t == 3) ? W222 : W212;
                v = W[ch * 16 + c];
            }
        } else if (i < 16896) v = W1[i - 8704];
        else if (i < 33280) v = W2[i - 16896];
        else if (i < 41472) v = W3[i - 33280];
        else v = Wdir[i - 41472];
        wout[i] = __float2bfloat16(v);
        return;
    }
    b -= 178;
    if (b < NPB) {
        __shared__ float sxa[256], sxv[384], sxd[576];
        const int n0 = b * 4;
        if (n0 + tid / 64 < N) sxa[tid] = xa[(size_t)n0 * 64 + tid];
        for (int i = tid; i < 384; i += 256) if (n0 + i / 96 < N)  sxv[i] = xv[(size_t)n0 * 96 + i];
        for (int i = tid; i < 576; i += 256) if (n0 + i / 144 < N) sxd[i] = xd[(size_t)n0 * 144 + i];
        __syncthreads();
        for (int o = tid; o < 832; o += 256) {
            int ln = o / 208, s = o % 208;
            int n = n0 + ln;
            if (n >= N) continue;
            if (s < 16) {
                float a = 0.f;
                const float* w = WL0 + s * 64;
                const float* x = sxa + ln * 64;
                for (int d = 0; d < 64; ++d) a += w[d] * x[d];
                Pa[(size_t)n * 16 + s] = a;
            } else if (s < 64) {
                int idx = s - 16, c = idx / 3, i = idx % 3;
                float a = 0.f;
                const float* w = WL1 + c * 32;
                const float* x = sxv + ln * 96;
                for (int d = 0; d < 32; ++d) a += w[d] * x[d * 3 + i];
                Pv[(size_t)n * 64 + c * 4 + i] = a;
            } else {
                int idx = s - 64, c = idx / 9, ij = idx % 9;
                float a = 0.f;
                const float* w = WL2 + c * 16;
                const float* x = sxd + ln * 144;
                for (int d = 0; d < 16; ++d) a += w[d] * x[d * 9 + ij];
                Pd[(size_t)n * 192 + c * 12 + ij] = a;
            }
        }
        return;
    }
    b -= NPB;
    int i = b * 256 + tid;
    if (i < E) {
        atomicAdd(&cnt_s[src[i]], 1);
        atomicAdd(&cnt_d[dst[i]], 1);
    }
}

// --------------------------------------------------------------- CSR ----
__global__ void scan_rows2(const int* __restrict__ cnt_s, int* __restrict__ rs_s,
                           const int* __restrict__ cnt_d, int* __restrict__ rs_d, int N) {
    const int* cnt = blockIdx.x ? cnt_d : cnt_s;
    int* rowstart = blockIdx.x ? rs_d : rs_s;
    __shared__ int ps[256];
    int t = threadIdx.x;
    int chunk = (N + 255) / 256;
    int base = t * chunk;
    int s = 0;
    for (int i = 0; i < chunk; ++i) { int idx = base + i; if (idx < N) s += cnt[idx]; }
    ps[t] = s;
    __syncthreads();
    for (int off = 1; off < 256; off <<= 1) {
        int v = (t >= off) ? ps[t - off] : 0;
        __syncthreads();
        ps[t] += v;
        __syncthreads();
    }
    int run = (t > 0) ? ps[t - 1] : 0;
    for (int i = 0; i < chunk; ++i) {
        int idx = base + i;
        if (idx < N) { rowstart[idx] = run; run += cnt[idx]; }
    }
    if (t == 255) rowstart[N] = run;
}

__global__ void fill_slot(const int* __restrict__ src, const int* __restrict__ dst,
                          const int* __restrict__ rs_s, const int* __restrict__ rs_d,
                          int* __restrict__ cur_s, int* __restrict__ cur_d,
                          int* __restrict__ slot, int* __restrict__ eperm, int E) {
    int i = blockIdx.x * 256 + threadIdx.x;
    if (i < E) {
        slot[i] = rs_s[src[i]] + atomicAdd(&cur_s[src[i]], 1);
        int p = rs_d[dst[i]] + atomicAdd(&cur_d[dst[i]], 1);
        eperm[p] = i;
    }
}

// ---------------------------------------------------------- edge_mfma ----
// Round-9 structure (best known): 16 edges/block, dst-sorted order, XCD
// swizzle. + factored Gaussian radial (2 exps instead of 8) and setprio
// around MFMA clusters (role-split waves in phase 2).
__global__ __launch_bounds__(256) void edge_mfma(
    const float* __restrict__ r_ij,
    const float* __restrict__ Pa, const float* __restrict__ Pv, const float* __restrict__ Pd,
    const float* __restrict__ WencP, const float* __restrict__ benc,
    const bf16* __restrict__ Wa, const bf16* __restrict__ Wv, const bf16* __restrict__ Wd,
    const bf16* __restrict__ Wb1, const bf16* __restrict__ Wb2,
    const bf16* __restrict__ Wb3, const bf16* __restrict__ Wbdir,
    const float* __restrict__ b1, const float* __restrict__ b2, const float* __restrict__ b3,
    const int* __restrict__ slot, const int* __restrict__ dst,
    const int* __restrict__ eperm,
    short* __restrict__ psi, int E, int nwg)
{
    __shared__ __align__(16) char smem[32320];
    short* SYA   = (short*)smem;            // [16][48]
    short* SYV   = (short*)(smem + 1536);   // [48][80]
    short* SYD   = (short*)(smem + 9216);   // [144][80]
    int*   SSLOT = (int*)(smem + 32256);    // [16]
    // phase-3 aliases (valid after b2)
    short* SPSIA = (short*)(smem + 1536);   // [16][72]
    short* SH1   = (short*)(smem + 3840);   // [16][136]
    short* SH2   = (short*)(smem + 8192);   // [16][136]
    short* SPSI  = (short*)(smem + 12544);  // [16][304]

    const int tid = threadIdx.x;
    // bijective XCD swizzle (m204)
    int orig = blockIdx.x;
    int q = nwg >> 3, r = nwg & 7;
    int xcd = orig & 7, idx = orig >> 3;
    int tile = (xcd < r) ? (xcd * (q + 1) + idx) : (r * (q + 1) + (xcd - r) * q + idx);
    const int e0 = tile * 16;
    const bf16x8 z8 = {};

    // ---- phase 1: y-build. thread = (local edge le, channel c)
    {
        const int le = tid >> 4, c = tid & 15;
        if (e0 + le < E) {
            const int e = eperm[e0 + le];
            const int j = dst[e];
            if (c == 0) SSLOT[le] = slot[e];
            float vx = 7.f * r_ij[e * 3 + 0];
            float vy = 7.f * r_ij[e * 3 + 1];
            float vz = 7.f * r_ij[e * 3 + 2];
            float nn = sqrtf(vx * vx + vy * vy + vz * vz);
            float ex = __expf(-2.f * nn);
            float th = (1.f - ex) * __builtin_amdgcn_rcpf(1.f + ex);
            float sc = th * __builtin_amdgcn_rcpf(nn + 1e-12f);
            float rr[3] = {vx * sc, vy * sc, vz * sc};
            // factored radial: e_m = exp(-x^2/2) * exp(x)^m * exp(-m^2/2);
            // the constant is folded into WencP. x clamped to 12 (all terms
            // < e^-12.5 there, matching the true values' negligibility).
            float xc = fminf(nn * (8.f / 7.f), 12.f);
            float T = __expf(xc);
            float pm = __expf(-0.5f * xc * xc);
            float rad = benc[c];
            #pragma unroll
            for (int m = 0; m < 8; ++m) {
                rad = fmaf(pm, WencP[c * 8 + m], rad);
                pm *= T;
            }
            float xa = Pa[j * 16 + c];
            f32x4 pv4 = *(const f32x4*)(Pv + (size_t)j * 64 + c * 4);
            f32x4 pd0 = *(const f32x4*)(Pd + (size_t)j * 192 + c * 12);
            f32x4 pd1 = *(const f32x4*)(Pd + (size_t)j * 192 + c * 12 + 4);
            f32x4 pd2 = *(const f32x4*)(Pd + (size_t)j * 192 + c * 12 + 8);
            float xv[3] = {pv4[0], pv4[1], pv4[2]};
            float xd[9] = {pd0[0], pd0[1], pd0[2], pd0[3], pd1[0], pd1[1], pd1[2], pd1[3], pd2[0]};
            float dotv = xv[0] * rr[0] + xv[1] * rr[1] + xv[2] * rr[2];
            float mv[3];
            #pragma unroll
            for (int i = 0; i < 3; ++i)
                mv[i] = xd[i * 3] * rr[0] + xd[i * 3 + 1] * rr[1] + xd[i * 3 + 2] * rr[2];
            float quad = mv[0] * rr[0] + mv[1] * rr[1] + mv[2] * rr[2];
            st_bf16(&SYA[le * 48 + c],      xa * rad);
            st_bf16(&SYA[le * 48 + 16 + c], rad * dotv);
            st_bf16(&SYA[le * 48 + 32 + c], rad * quad);
            #pragma unroll
            for (int i = 0; i < 3; ++i) {
                int row = (le * 3 + i) * 80;
                int i1 = (i + 1) % 3, i2 = (i + 2) % 3;
                st_bf16(&SYV[row + c],      xa * rad * rr[i]);
                st_bf16(&SYV[row + 16 + c], rad * xv[i]);
                st_bf16(&SYV[row + 32 + c], rad * dotv * rr[i]);
                st_bf16(&SYV[row + 48 + c], rad * mv[i]);
                st_bf16(&SYV[row + 64 + c], rad * (xv[i1] * rr[i2] - xv[i2] * rr[i1]));
            }
            #pragma unroll
            for (int i = 0; i < 3; ++i) {
                int i1 = (i + 1) % 3, i2 = (i + 2) % 3;
                #pragma unroll
                for (int jj = 0; jj < 3; ++jj) {
                    int row = (le * 9 + i * 3 + jj) * 80;
                    st_bf16(&SYD[row + c],      xa * rad * rr[i] * rr[jj]);
                    st_bf16(&SYD[row + 16 + c], rad * xd[i * 3 + jj]);
                    st_bf16(&SYD[row + 32 + c], rad * xv[i] * rr[jj]);
                    st_bf16(&SYD[row + 48 + c], rad * mv[i] * rr[jj]);
                    st_bf16(&SYD[row + 64 + c], rad * (xd[i1 * 3 + jj] * rr[i2] - xd[i2 * 3 + jj] * rr[i1]));
                }
            }
        }
    }
    __syncthreads();   // b1: y ready

    // ---- phase 2: tensor GEMMs (accumulators persist across b2)
    const int wid = tid >> 6, lane = tid & 63;
    const int q16 = lane >> 4, r16 = lane & 15;

    f32x4 da[4] = {};
    f32x4 dv[3][2] = {};
    f32x4 dd[5] = {};
    const int mstart = (wid == 2) ? 0 : 5;
    const int mcnt = (wid == 2) ? 5 : 4;

    __builtin_amdgcn_s_setprio(1);
    if (wid == 0) {
        bf16x8 af0 = *(const bf16x8*)&SYA[r16 * 48 + q16 * 8];
        bf16x8 af1 = z8;
        if (q16 < 2) af1 = *(const bf16x8*)&SYA[r16 * 48 + 32 + q16 * 8];
        #pragma unroll
        for (int n = 0; n < 4; ++n) {
            bf16x8 bf0 = *(const bf16x8*)((const short*)Wa + (n * 16 + r16) * 64 + q16 * 8);
            bf16x8 bf1 = *(const bf16x8*)((const short*)Wa + (n * 16 + r16) * 64 + 32 + q16 * 8);
            da[n] = __builtin_amdgcn_mfma_f32_16x16x32_bf16(af0, bf0, da[n], 0, 0, 0);
            da[n] = __builtin_amdgcn_mfma_f32_16x16x32_bf16(af1, bf1, da[n], 0, 0, 0);
        }
    } else if (wid == 1) {
        #pragma unroll
        for (int ks = 0; ks < 3; ++ks) {
            bf16x8 av[3], bv[2];
            #pragma unroll
            for (int m = 0; m < 3; ++m) {
                if (ks < 2) av[m] = *(const bf16x8*)&SYV[(m * 16 + r16) * 80 + ks * 32 + q16 * 8];
                else {
                    av[m] = z8;
                    if (q16 < 2) av[m] = *(const bf16x8*)&SYV[(m * 16 + r16) * 80 + 64 + q16 * 8];
                }
            }
            #pragma unroll
            for (int n = 0; n < 2; ++n)
                bv[n] = *(const bf16x8*)((const short*)Wv + (n * 16 + r16) * 96 + ks * 32 + q16 * 8);
            #pragma unroll
            for (int m = 0; m < 3; ++m)
                #pragma unroll
                for (int n = 0; n < 2; ++n)
                    dv[m][n] = __builtin_amdgcn_mfma_f32_16x16x32_bf16(av[m], bv[n], dv[m][n], 0, 0, 0);
        }
    } else {
        #pragma unroll
        for (int ks = 0; ks < 3; ++ks) {
            bf16x8 bf = *(const bf16x8*)((const short*)Wd + r16 * 96 + ks * 32 + q16 * 8);
            for (int mi = 0; mi < mcnt; ++mi) {
                bf16x8 af;
                if (ks < 2) af = *(const bf16x8*)&SYD[((mstart + mi) * 16 + r16) * 80 + ks * 32 + q16 * 8];
                else {
                    af = z8;
                    if (q16 < 2) af = *(const bf16x8*)&SYD[((mstart + mi) * 16 + r16) * 80 + 64 + q16 * 8];
                }
                dd[mi] = __builtin_amdgcn_mfma_f32_16x16x32_bf16(af, bf, dd[mi], 0, 0, 0);
            }
        }
    }
    __builtin_amdgcn_s_setprio(0);
    __syncthreads();   // b2: y reads done, alias region reusable

    // ---- epilogues into aliased region
    if (wid == 0) {
        #pragma unroll
        for (int n = 0; n < 4; ++n)
            #pragma unroll
            for (int jj = 0; jj < 4; ++jj)
                st_bf16(&SPSIA[(q16 * 4 + jj) * 72 + n * 16 + r16], da[n][jj]);
    } else if (wid == 1) {
        #pragma unroll
        for (int m = 0; m < 3; ++m)
            #pragma unroll
            for (int n = 0; n < 2; ++n)
                #pragma unroll
                for (int jj = 0; jj < 4; ++jj) {
                    int row = m * 16 + q16 * 4 + jj;
                    int el = row / 3, i = row % 3;
                    st_bf16(&SPSI[el * 304 + 64 + (n * 16 + r16) * 3 + i], dv[m][n][jj]);
                }
    } else {
        for (int mi = 0; mi < mcnt; ++mi)
            #pragma unroll
            for (int jj = 0; jj < 4; ++jj) {
                int row = (mstart + mi) * 16 + q16 * 4 + jj;
                int el = row / 9, ij = row % 9;
                st_bf16(&SPSI[el * 304 + 160 + r16 * 9 + ij], dd[mi][jj]);
            }
    }
    __syncthreads();   // b3: psi_a + psi_v/d staged

    // ---- phase 3: fused MLP (M=16, waves split N)
    {
        f32x4 h1a[2] = {};
        __builtin_amdgcn_s_setprio(1);
        #pragma unroll
        for (int ks = 0; ks < 2; ++ks) {
            bf16x8 af = *(const bf16x8*)&SPSIA[r16 * 72 + ks * 32 + q16 * 8];
            #pragma unroll
            for (int n = 0; n < 2; ++n) {
                int col = wid * 32 + n * 16 + r16;
                bf16x8 bf = *(const bf16x8*)((const short*)Wb1 + col * 64 + ks * 32 + q16 * 8);
                h1a[n] = __builtin_amdgcn_mfma_f32_16x16x32_bf16(af, bf, h1a[n], 0, 0, 0);
            }
        }
        __builtin_amdgcn_s_setprio(0);
        #pragma unroll
        for (int n = 0; n < 2; ++n) {
            int col = wid * 32 + n * 16 + r16;
            float bias = b1[col];
            #pragma unroll
            for (int jj = 0; jj < 4; ++jj) {
                float v = h1a[n][jj] + bias;
                v = v >= 0.f ? v : 0.1f * v;
                st_bf16(&SH1[(q16 * 4 + jj) * 136 + col], v);
            }
        }
    }
    __syncthreads();   // b4: h1 ready
    {
        f32x4 h2a[2] = {};
        __builtin_amdgcn_s_setprio(1);
        #pragma unroll
        for (int ks = 0; ks < 4; ++ks) {
            bf16x8 af = *(const bf16x8*)&SH1[r16 * 136 + ks * 32 + q16 * 8];
            #pragma unroll
            for (int n = 0; n < 2; ++n) {
                int col = wid * 32 + n * 16 + r16;
                bf16x8 bf = *(const bf16x8*)((const short*)Wb2 + col * 128 + ks * 32 + q16 * 8);
                h2a[n] = __builtin_amdgcn_mfma_f32_16x16x32_bf16(af, bf, h2a[n], 0, 0, 0);
            }
        }
        __builtin_amdgcn_s_setprio(0);
        #pragma unroll
        for (int n = 0; n < 2; ++n) {
            int col = wid * 32 + n * 16 + r16;
            float bias = b2[col];
            #pragma unroll
            for (int jj = 0; jj < 4; ++jj) {
                float v = h2a[n][jj] + bias;
                v = v >= 0.f ? v : 0.1f * v;
                st_bf16(&SH2[(q16 * 4 + jj) * 136 + col], v);
            }
        }
    }
    __syncthreads();   // b5: h2 ready
    {
        f32x4 o3 = {};
        const int col3 = wid * 16 + r16;
        __builtin_amdgcn_s_setprio(1);
        #pragma unroll
        for (int ks = 0; ks < 4; ++ks) {
            bf16x8 af = *(const bf16x8*)&SH2[r16 * 136 + ks * 32 + q16 * 8];
            bf16x8 bf = *(const bf16x8*)((const short*)Wb3 + col3 * 128 + ks * 32 + q16 * 8);
            o3 = __builtin_amdgcn_mfma_f32_16x16x32_bf16(af, bf, o3, 0, 0, 0);
        }
        #pragma unroll
        for (int ks = 0; ks < 2; ++ks) {
            bf16x8 af = *(const bf16x8*)&SPSIA[r16 * 72 + ks * 32 + q16 * 8];
            bf16x8 bf = *(const bf16x8*)((const short*)Wbdir + col3 * 64 + ks * 32 + q16 * 8);
            o3 = __builtin_amdgcn_mfma_f32_16x16x32_bf16(af, bf, o3, 0, 0, 0);
        }
        __builtin_amdgcn_s_setprio(0);
        float bias = b3[col3];
        #pragma unroll
        for (int jj = 0; jj < 4; ++jj) {
            int row = q16 * 4 + jj;
            float v = o3[jj] + bias + bb2f(SPSIA[row * 72 + col3]);
            st_bf16(&SPSI[row * 304 + col3], v);
        }
    }
    __syncthreads();   // b6: SPSI complete

    // ---- coalesced psi-row store at CSR slot
    {
        const uint32_t* S32 = (const uint32_t*)SPSI;
        uint32_t* P32 = (uint32_t*)psi;
        for (int idx2 = tid; idx2 < 16 * 152; idx2 += 256) {
            int le = idx2 / 152, k = idx2 - le * 152;
            if (e0 + le < E)
                P32[(size_t)SSLOT[le] * 152 + k] = S32[le * 152 + k];
        }
    }
}

// -------------------------------------------------------------- gather ----
__global__ __launch_bounds__(128) void gather(
    const short* __restrict__ psi, const int* __restrict__ rowstart,
    float* __restrict__ out, int N) {
    int n = blockIdx.x, t = threadIdx.x;
    if (t >= 76) return;
    int s0 = rowstart[n], s1 = rowstart[n + 1];
    float a0 = 0.f, a1 = 0.f, a2 = 0.f, a3 = 0.f;
    for (int s = s0; s < s1; ++s) {
        const uint32_t* p = (const uint32_t*)(psi + (size_t)s * 304) + 2 * t;
        uint32_t u0 = p[0], u1 = p[1];
        a0 += __uint_as_float(u0 << 16);
        a1 += __uint_as_float(u0 & 0xffff0000u);
        a2 += __uint_as_float(u1 << 16);
        a3 += __uint_as_float(u1 & 0xffff0000u);
    }
    int f = 4 * t;
    f32x4 v = {0.1f * a0, 0.1f * a1, 0.1f * a2, 0.1f * a3};
    if (f < 64)       *(f32x4*)&out[(size_t)n * 64 + f] = v;
    else if (f < 160) *(f32x4*)&out[(size_t)N * 64 + (size_t)n * 96 + (f - 64)] = v;
    else              *(f32x4*)&out[(size_t)N * 160 + (size_t)n * 144 + (f - 160)] = v;
}

// -------------------------------------------------------------- launch ----
extern "C" void kernel_launch(void* const* d_in, const int* in_sizes, int n_in,
                              void* d_out, int out_size, void* d_ws, size_t ws_size,
                              hipStream_t stream) {
    const float* r_ij = (const float*)d_in[0];
    const float* x_a  = (const float*)d_in[1];
    const float* x_v  = (const float*)d_in[2];
    const float* x_d  = (const float*)d_in[3];
    const float* W_L0 = (const float*)d_in[4];
    const float* W_L1 = (const float*)d_in[5];
    const float* W_L2 = (const float*)d_in[6];
    const float* W000 = (const float*)d_in[7];
    const float* W110 = (const float*)d_in[8];
    const float* W220 = (const float*)d_in[9];
    const float* W011 = (const float*)d_in[10];
    const float* W101 = (const float*)d_in[11];
    const float* W121 = (const float*)d_in[12];
    const float* W211 = (const float*)d_in[13];
    const float* W022 = (const float*)d_in[14];
    const float* W202 = (const float*)d_in[15];
    const float* W112 = (const float*)d_in[16];
    const float* W222 = (const float*)d_in[17];
    const float* W111 = (const float*)d_in[18];
    const float* W212 = (const float*)d_in[19];
    const float* Wenc = (const float*)d_in[20];
    const float* benc = (const float*)d_in[21];
    const float* Wdir = (const float*)d_in[22];
    const float* W1   = (const float*)d_in[23];
    const float* b1   = (const float*)d_in[24];
    const float* W2   = (const float*)d_in[25];
    const float* b2   = (const float*)d_in[26];
    const float* W3   = (const float*)d_in[27];
    const float* b3   = (const float*)d_in[28];
    const int* src    = (const int*)d_in[29];
    const int* dst    = (const int*)d_in[30];

    const int E = in_sizes[29];
    const int N = in_sizes[1] / 64;

    // ws layout
    float* Pa     = (float*)d_ws;                    // N*16
    float* Pv     = Pa + (size_t)N * 16;             // N*64
    float* Pd     = Pv + (size_t)N * 64;             // N*192
    bf16*  Wb     = (bf16*)(Pd + (size_t)N * 192);   // 45568 bf16
    float* WencP  = (float*)(Wb + 45568);            // 128 f32
    int*   cnt_s  = (int*)(WencP + 128);             // N
    int*   cur_s  = cnt_s + N;                       // N
    int*   cnt_d  = cur_s + N;                       // N
    int*   cur_d  = cnt_d + N;                       // N
    int*   rs_s   = cur_d + N;                       // N+1
    int*   rs_d   = rs_s + N + 1;                    // N+1
    int*   slot   = rs_d + N + 1;                    // E
    int*   eperm  = slot + E;                        // E
    short* psi    = (short*)(eperm + E);             // E*304 bf16

    const bf16* Wa_p    = Wb;
    const bf16* Wv_p    = Wb + 4096;
    const bf16* Wd_p    = Wb + 7168;
    const bf16* Wb1_p   = Wb + 8704;
    const bf16* Wb2_p   = Wb + 16896;
    const bf16* Wb3_p   = Wb + 33280;
    const bf16* Wbdir_p = Wb + 41472;

    const int NPB = (N + 3) / 4;
    const int HB  = (E + 255) / 256;
    const int nwg = (E + 15) / 16;

    hipMemsetAsync(cnt_s, 0, (size_t)4 * N * sizeof(int), stream);
    prep_all<<<178 + NPB + HB, 256, 0, stream>>>(
        W000, W110, W220, W011, W101, W121, W211, W111,
        W022, W202, W112, W222, W212, W1, W2, W3, Wdir, Wb,
        Wenc, WencP,
        x_a, x_v, x_d, W_L0, W_L1, W_L2, Pa, Pv, Pd, N, NPB,
        src, dst, cnt_s, cnt_d, E);
    scan_rows2<<<2, 256, 0, stream>>>(cnt_s, rs_s, cnt_d, rs_d, N);
    fill_slot<<<HB, 256, 0, stream>>>(src, dst, rs_s, rs_d, cur_s, cur_d, slot, eperm, E);
    edge_mfma<<<nwg, 256, 0, stream>>>(
        r_ij, Pa, Pv, Pd, WencP, benc,
        Wa_p, Wv_p, Wd_p, Wb1_p, Wb2_p, Wb3_p, Wbdir_p,
        b1, b2, b3, slot, dst, eperm, psi, E, nwg);
    gather<<<N, 128, 0, stream>>>(psi, rs_s, (float*)d_out, N);
}

// Round 13
// 230.053 us; speedup vs baseline: 2.2292x; 1.1289x over previous
//
#include <hip/hip_runtime.h>
#include <hip/hip_bf16.h>

typedef __hip_bfloat16 bf16;
typedef __attribute__((ext_vector_type(8))) short bf16x8;
typedef __attribute__((ext_vector_type(4))) float f32x4;

__device__ __forceinline__ void st_bf16(short* p, float v) {
    uint32_t u = __float_as_uint(v) + 0x8000u;
    *p = (short)(u >> 16);
}
__device__ __forceinline__ float bb2f(short s) {
    uint32_t u = ((uint32_t)(uint16_t)s) << 16;
    return __uint_as_float(u);
}

// ------------------------------------------------------------- prep_all ----
// blockIdx ranges: [0,178) prep_w | [178, 178+NPB) node_proj (padded P out)
//                  | rest: histogram of src
__global__ __launch_bounds__(256) void prep_all(
    const float* __restrict__ W000, const float* __restrict__ W110, const float* __restrict__ W220,
    const float* __restrict__ W011, const float* __restrict__ W101, const float* __restrict__ W121,
    const float* __restrict__ W211, const float* __restrict__ W111,
    const float* __restrict__ W022, const float* __restrict__ W202, const float* __restrict__ W112,
    const float* __restrict__ W222, const float* __restrict__ W212,
    const float* __restrict__ W1, const float* __restrict__ W2, const float* __restrict__ W3,
    const float* __restrict__ Wdir, bf16* __restrict__ wout,
    const float* __restrict__ xa, const float* __restrict__ xv, const float* __restrict__ xd,
    const float* __restrict__ WL0, const float* __restrict__ WL1, const float* __restrict__ WL2,
    float* __restrict__ Pa, float* __restrict__ Pv, float* __restrict__ Pd, int N, int NPB,
    const int* __restrict__ src, int* __restrict__ cnt, int E)
{
    int b = blockIdx.x;
    const int tid = threadIdx.x;
    if (b < 178) {
        // ---- weight packing (bf16, K zero-padded)
        int i = b * 256 + tid;
        if (i >= 45568) return;
        float v = 0.f;
        if (i < 4096) {
            int o = i >> 6, k = i & 63;
            if (k < 48) {
                int t = k >> 4, c = k & 15;
                const float* W = (t == 0) ? W000 : (t == 1) ? W110 : W220;
                v = W[o * 16 + c];
            }
        } else if (i < 7168) {
            int r = i - 4096, ch = r / 96, k = r % 96;
            if (k < 80) {
                int t = k >> 4, c = k & 15;
                const float* W = (t == 0) ? W011 : (t == 1) ? W101 : (t == 2) ? W121 : (t == 3) ? W211 : W111;
                v = W[ch * 16 + c];
            }
        } else if (i < 8704) {
            int r = i - 7168, ch = r / 96, k = r % 96;
            if (k < 80) {
                int t = k >> 4, c = k & 15;
                const float* W = (t == 0) ? W022 : (t == 1) ? W202 : (t == 2) ? W112 : (t == 3) ? W222 : W212;
                v = W[ch * 16 + c];
            }
        } else if (i < 16896) v = W1[i - 8704];
        else if (i < 33280) v = W2[i - 16896];
        else if (i < 41472) v = W3[i - 33280];
        else v = Wdir[i - 41472];
        wout[i] = __float2bfloat16(v);
        return;
    }
    b -= 178;
    if (b < NPB) {
        // ---- node projection, 4 nodes/block, padded output layouts
        __shared__ float sxa[256], sxv[384], sxd[576];
        const int n0 = b * 4;
        if (n0 + tid / 64 < N) sxa[tid] = xa[(size_t)n0 * 64 + tid];
        for (int i = tid; i < 384; i += 256) if (n0 + i / 96 < N)  sxv[i] = xv[(size_t)n0 * 96 + i];
        for (int i = tid; i < 576; i += 256) if (n0 + i / 144 < N) sxd[i] = xd[(size_t)n0 * 144 + i];
        __syncthreads();
        for (int o = tid; o < 832; o += 256) {
            int ln = o / 208, s = o % 208;
            int n = n0 + ln;
            if (n >= N) continue;
            if (s < 16) {
                float a = 0.f;
                const float* w = WL0 + s * 64;
                const float* x = sxa + ln * 64;
                for (int d = 0; d < 64; ++d) a += w[d] * x[d];
                Pa[(size_t)n * 16 + s] = a;
            } else if (s < 64) {
                int idx = s - 16, c = idx / 3, i = idx % 3;
                float a = 0.f;
                const float* w = WL1 + c * 32;
                const float* x = sxv + ln * 96;
                for (int d = 0; d < 32; ++d) a += w[d] * x[d * 3 + i];
                Pv[(size_t)n * 64 + c * 4 + i] = a;
            } else {
                int idx = s - 64, c = idx / 9, ij = idx % 9;
                float a = 0.f;
                const float* w = WL2 + c * 16;
                const float* x = sxd + ln * 144;
                for (int d = 0; d < 16; ++d) a += w[d] * x[d * 9 + ij];
                Pd[(size_t)n * 192 + c * 12 + ij] = a;
            }
        }
        return;
    }
    b -= NPB;
    // ---- histogram of src
    int i = b * 256 + tid;
    if (i < E) atomicAdd(&cnt[src[i]], 1);
}

// --------------------------------------------------------------- CSR ----
__global__ void scan_rows(const int* __restrict__ cnt, int* __restrict__ rowstart, int N) {
    __shared__ int ps[256];
    int t = threadIdx.x;
    int chunk = (N + 255) / 256;
    int base = t * chunk;
    int s = 0;
    for (int i = 0; i < chunk; ++i) { int idx = base + i; if (idx < N) s += cnt[idx]; }
    ps[t] = s;
    __syncthreads();
    for (int off = 1; off < 256; off <<= 1) {
        int v = (t >= off) ? ps[t - off] : 0;
        __syncthreads();
        ps[t] += v;
        __syncthreads();
    }
    int run = (t > 0) ? ps[t - 1] : 0;
    for (int i = 0; i < chunk; ++i) {
        int idx = base + i;
        if (idx < N) { rowstart[idx] = run; run += cnt[idx]; }
    }
    if (t == 255) rowstart[N] = run;
}

// ---------------------------------------------------------- edge_mfma ----
// r8 structure (best known): 16 edges/block, natural order, ~32.3KB LDS.
// CSR output slot computed INLINE (rs[src[e]] + atomicAdd(cursor)) — no
// separate fill_slot pass.
__global__ __launch_bounds__(256) void edge_mfma(
    const float* __restrict__ r_ij,
    const float* __restrict__ Pa, const float* __restrict__ Pv, const float* __restrict__ Pd,
    const float* __restrict__ Wenc, const float* __restrict__ benc,
    const bf16* __restrict__ Wa, const bf16* __restrict__ Wv, const bf16* __restrict__ Wd,
    const bf16* __restrict__ Wb1, const bf16* __restrict__ Wb2,
    const bf16* __restrict__ Wb3, const bf16* __restrict__ Wbdir,
    const float* __restrict__ b1, const float* __restrict__ b2, const float* __restrict__ b3,
    const int* __restrict__ src, const int* __restrict__ dst,
    const int* __restrict__ rs, int* __restrict__ cur,
    short* __restrict__ psi, int E)
{
    __shared__ __align__(16) char smem[32320];
    short* SYA   = (short*)smem;            // [16][48]
    short* SYV   = (short*)(smem + 1536);   // [48][80]
    short* SYD   = (short*)(smem + 9216);   // [144][80]
    int*   SSLOT = (int*)(smem + 32256);    // [16]
    // phase-3 aliases (valid after b2)
    short* SPSIA = (short*)(smem + 1536);   // [16][72]
    short* SH1   = (short*)(smem + 3840);   // [16][136]
    short* SH2   = (short*)(smem + 8192);   // [16][136]
    short* SPSI  = (short*)(smem + 12544);  // [16][304]

    const int tid = threadIdx.x;
    const int e0 = blockIdx.x * 16;
    const bf16x8 z8 = {};

    // ---- phase 1: y-build. thread = (local edge le, channel c)
    {
        const int le = tid >> 4, c = tid & 15;
        const int e = e0 + le;
        if (e < E) {
            const int j = dst[e];
            if (c == 0) SSLOT[le] = rs[src[e]] + atomicAdd(&cur[src[e]], 1);
            float vx = 7.f * r_ij[e * 3 + 0];
            float vy = 7.f * r_ij[e * 3 + 1];
            float vz = 7.f * r_ij[e * 3 + 2];
            float nn = sqrtf(vx * vx + vy * vy + vz * vz);
            float ex = __expf(-2.f * nn);
            float th = (1.f - ex) * __builtin_amdgcn_rcpf(1.f + ex);
            float sc = th * __builtin_amdgcn_rcpf(nn + 1e-12f);
            float rr[3] = {vx * sc, vy * sc, vz * sc};
            float x8 = nn * (8.f / 7.f);
            float rad = benc[c];
            #pragma unroll
            for (int m = 0; m < 8; ++m) {
                float tt = x8 - (float)m;
                rad += __expf(-0.5f * tt * tt) * Wenc[c * 8 + m];
            }
            float xa = Pa[j * 16 + c];
            f32x4 pv4 = *(const f32x4*)(Pv + (size_t)j * 64 + c * 4);
            f32x4 pd0 = *(const f32x4*)(Pd + (size_t)j * 192 + c * 12);
            f32x4 pd1 = *(const f32x4*)(Pd + (size_t)j * 192 + c * 12 + 4);
            f32x4 pd2 = *(const f32x4*)(Pd + (size_t)j * 192 + c * 12 + 8);
            float xv[3] = {pv4[0], pv4[1], pv4[2]};
            float xd[9] = {pd0[0], pd0[1], pd0[2], pd0[3], pd1[0], pd1[1], pd1[2], pd1[3], pd2[0]};
            float dotv = xv[0] * rr[0] + xv[1] * rr[1] + xv[2] * rr[2];
            float mv[3];
            #pragma unroll
            for (int i = 0; i < 3; ++i)
                mv[i] = xd[i * 3] * rr[0] + xd[i * 3 + 1] * rr[1] + xd[i * 3 + 2] * rr[2];
            float quad = mv[0] * rr[0] + mv[1] * rr[1] + mv[2] * rr[2];
            st_bf16(&SYA[le * 48 + c],      xa * rad);
            st_bf16(&SYA[le * 48 + 16 + c], rad * dotv);
            st_bf16(&SYA[le * 48 + 32 + c], rad * quad);
            #pragma unroll
            for (int i = 0; i < 3; ++i) {
                int row = (le * 3 + i) * 80;
                int i1 = (i + 1) % 3, i2 = (i + 2) % 3;
                st_bf16(&SYV[row + c],      xa * rad * rr[i]);
                st_bf16(&SYV[row + 16 + c], rad * xv[i]);
                st_bf16(&SYV[row + 32 + c], rad * dotv * rr[i]);
                st_bf16(&SYV[row + 48 + c], rad * mv[i]);
                st_bf16(&SYV[row + 64 + c], rad * (xv[i1] * rr[i2] - xv[i2] * rr[i1]));
            }
            #pragma unroll
            for (int i = 0; i < 3; ++i) {
                int i1 = (i + 1) % 3, i2 = (i + 2) % 3;
                #pragma unroll
                for (int jj = 0; jj < 3; ++jj) {
                    int row = (le * 9 + i * 3 + jj) * 80;
                    st_bf16(&SYD[row + c],      xa * rad * rr[i] * rr[jj]);
                    st_bf16(&SYD[row + 16 + c], rad * xd[i * 3 + jj]);
                    st_bf16(&SYD[row + 32 + c], rad * xv[i] * rr[jj]);
                    st_bf16(&SYD[row + 48 + c], rad * mv[i] * rr[jj]);
                    st_bf16(&SYD[row + 64 + c], rad * (xd[i1 * 3 + jj] * rr[i2] - xd[i2 * 3 + jj] * rr[i1]));
                }
            }
        }
    }
    __syncthreads();   // b1: y ready

    // ---- phase 2: tensor GEMMs (accumulators persist across b2)
    const int wid = tid >> 6, lane = tid & 63;
    const int q16 = lane >> 4, r16 = lane & 15;

    f32x4 da[4] = {};
    f32x4 dv[3][2] = {};
    f32x4 dd[5] = {};
    const int mstart = (wid == 2) ? 0 : 5;
    const int mcnt = (wid == 2) ? 5 : 4;

    if (wid == 0) {
        bf16x8 af0 = *(const bf16x8*)&SYA[r16 * 48 + q16 * 8];
        bf16x8 af1 = z8;
        if (q16 < 2) af1 = *(const bf16x8*)&SYA[r16 * 48 + 32 + q16 * 8];
        #pragma unroll
        for (int n = 0; n < 4; ++n) {
            bf16x8 bf0 = *(const bf16x8*)((const short*)Wa + (n * 16 + r16) * 64 + q16 * 8);
            bf16x8 bf1 = *(const bf16x8*)((const short*)Wa + (n * 16 + r16) * 64 + 32 + q16 * 8);
            da[n] = __builtin_amdgcn_mfma_f32_16x16x32_bf16(af0, bf0, da[n], 0, 0, 0);
            da[n] = __builtin_amdgcn_mfma_f32_16x16x32_bf16(af1, bf1, da[n], 0, 0, 0);
        }
    } else if (wid == 1) {
        #pragma unroll
        for (int ks = 0; ks < 3; ++ks) {
            bf16x8 av[3], bv[2];
            #pragma unroll
            for (int m = 0; m < 3; ++m) {
                if (ks < 2) av[m] = *(const bf16x8*)&SYV[(m * 16 + r16) * 80 + ks * 32 + q16 * 8];
                else {
                    av[m] = z8;
                    if (q16 < 2) av[m] = *(const bf16x8*)&SYV[(m * 16 + r16) * 80 + 64 + q16 * 8];
                }
            }
            #pragma unroll
            for (int n = 0; n < 2; ++n)
                bv[n] = *(const bf16x8*)((const short*)Wv + (n * 16 + r16) * 96 + ks * 32 + q16 * 8);
            #pragma unroll
            for (int m = 0; m < 3; ++m)
                #pragma unroll
                for (int n = 0; n < 2; ++n)
                    dv[m][n] = __builtin_amdgcn_mfma_f32_16x16x32_bf16(av[m], bv[n], dv[m][n], 0, 0, 0);
        }
    } else {
        #pragma unroll
        for (int ks = 0; ks < 3; ++ks) {
            bf16x8 bf = *(const bf16x8*)((const short*)Wd + r16 * 96 + ks * 32 + q16 * 8);
            for (int mi = 0; mi < mcnt; ++mi) {
                bf16x8 af;
                if (ks < 2) af = *(const bf16x8*)&SYD[((mstart + mi) * 16 + r16) * 80 + ks * 32 + q16 * 8];
                else {
                    af = z8;
                    if (q16 < 2) af = *(const bf16x8*)&SYD[((mstart + mi) * 16 + r16) * 80 + 64 + q16 * 8];
                }
                dd[mi] = __builtin_amdgcn_mfma_f32_16x16x32_bf16(af, bf, dd[mi], 0, 0, 0);
            }
        }
    }
    __syncthreads();   // b2: y reads done, alias region reusable

    // ---- epilogues into aliased region
    if (wid == 0) {
        #pragma unroll
        for (int n = 0; n < 4; ++n)
            #pragma unroll
            for (int jj = 0; jj < 4; ++jj)
                st_bf16(&SPSIA[(q16 * 4 + jj) * 72 + n * 16 + r16], da[n][jj]);
    } else if (wid == 1) {
        #pragma unroll
        for (int m = 0; m < 3; ++m)
            #pragma unroll
            for (int n = 0; n < 2; ++n)
                #pragma unroll
                for (int jj = 0; jj < 4; ++jj) {
                    int row = m * 16 + q16 * 4 + jj;
                    int el = row / 3, i = row % 3;
                    st_bf16(&SPSI[el * 304 + 64 + (n * 16 + r16) * 3 + i], dv[m][n][jj]);
                }
    } else {
        for (int mi = 0; mi < mcnt; ++mi)
            #pragma unroll
            for (int jj = 0; jj < 4; ++jj) {
                int row = (mstart + mi) * 16 + q16 * 4 + jj;
                int el = row / 9, ij = row % 9;
                st_bf16(&SPSI[el * 304 + 160 + r16 * 9 + ij], dd[mi][jj]);
            }
    }
    __syncthreads();   // b3: psi_a + psi_v/d staged

    // ---- phase 3: fused MLP (M=16, waves split N)
    {
        f32x4 h1a[2] = {};
        #pragma unroll
        for (int ks = 0; ks < 2; ++ks) {
            bf16x8 af = *(const bf16x8*)&SPSIA[r16 * 72 + ks * 32 + q16 * 8];
            #pragma unroll
            for (int n = 0; n < 2; ++n) {
                int col = wid * 32 + n * 16 + r16;
                bf16x8 bf = *(const bf16x8*)((const short*)Wb1 + col * 64 + ks * 32 + q16 * 8);
                h1a[n] = __builtin_amdgcn_mfma_f32_16x16x32_bf16(af, bf, h1a[n], 0, 0, 0);
            }
        }
        #pragma unroll
        for (int n = 0; n < 2; ++n) {
            int col = wid * 32 + n * 16 + r16;
            float bias = b1[col];
            #pragma unroll
            for (int jj = 0; jj < 4; ++jj) {
                float v = h1a[n][jj] + bias;
                v = v >= 0.f ? v : 0.1f * v;
                st_bf16(&SH1[(q16 * 4 + jj) * 136 + col], v);
            }
        }
    }
    __syncthreads();   // b4: h1 ready
    {
        f32x4 h2a[2] = {};
        #pragma unroll
        for (int ks = 0; ks < 4; ++ks) {
            bf16x8 af = *(const bf16x8*)&SH1[r16 * 136 + ks * 32 + q16 * 8];
            #pragma unroll
            for (int n = 0; n < 2; ++n) {
                int col = wid * 32 + n * 16 + r16;
                bf16x8 bf = *(const bf16x8*)((const short*)Wb2 + col * 128 + ks * 32 + q16 * 8);
                h2a[n] = __builtin_amdgcn_mfma_f32_16x16x32_bf16(af, bf, h2a[n], 0, 0, 0);
            }
        }
        #pragma unroll
        for (int n = 0; n < 2; ++n) {
            int col = wid * 32 + n * 16 + r16;
            float bias = b2[col];
            #pragma unroll
            for (int jj = 0; jj < 4; ++jj) {
                float v = h2a[n][jj] + bias;
                v = v >= 0.f ? v : 0.1f * v;
                st_bf16(&SH2[(q16 * 4 + jj) * 136 + col], v);
            }
        }
    }
    __syncthreads();   // b5: h2 ready
    {
        f32x4 o3 = {};
        const int col3 = wid * 16 + r16;
        #pragma unroll
        for (int ks = 0; ks < 4; ++ks) {
            bf16x8 af = *(const bf16x8*)&SH2[r16 * 136 + ks * 32 + q16 * 8];
            bf16x8 bf = *(const bf16x8*)((const short*)Wb3 + col3 * 128 + ks * 32 + q16 * 8);
            o3 = __builtin_amdgcn_mfma_f32_16x16x32_bf16(af, bf, o3, 0, 0, 0);
        }
        #pragma unroll
        for (int ks = 0; ks < 2; ++ks) {
            bf16x8 af = *(const bf16x8*)&SPSIA[r16 * 72 + ks * 32 + q16 * 8];
            bf16x8 bf = *(const bf16x8*)((const short*)Wbdir + col3 * 64 + ks * 32 + q16 * 8);
            o3 = __builtin_amdgcn_mfma_f32_16x16x32_bf16(af, bf, o3, 0, 0, 0);
        }
        float bias = b3[col3];
        #pragma unroll
        for (int jj = 0; jj < 4; ++jj) {
            int row = q16 * 4 + jj;
            float v = o3[jj] + bias + bb2f(SPSIA[row * 72 + col3]);
            st_bf16(&SPSI[row * 304 + col3], v);
        }
    }
    __syncthreads();   // b6: SPSI complete

    // ---- coalesced psi-row store at CSR slot
    {
        const uint32_t* S32 = (const uint32_t*)SPSI;
        uint32_t* P32 = (uint32_t*)psi;
        for (int idx2 = tid; idx2 < 16 * 152; idx2 += 256) {
            int le = idx2 / 152, k = idx2 - le * 152;
            if (e0 + le < E)
                P32[(size_t)SSLOT[le] * 152 + k] = S32[le * 152 + k];
        }
    }
}

// -------------------------------------------------------------- gather ----
// thread t (<76) handles dwords 2t,2t+1 of each row -> float4 output store
__global__ __launch_bounds__(128) void gather(
    const short* __restrict__ psi, const int* __restrict__ rowstart,
    float* __restrict__ out, int N) {
    int n = blockIdx.x, t = threadIdx.x;
    if (t >= 76) return;
    int s0 = rowstart[n], s1 = rowstart[n + 1];
    float a0 = 0.f, a1 = 0.f, a2 = 0.f, a3 = 0.f;
    for (int s = s0; s < s1; ++s) {
        const uint32_t* p = (const uint32_t*)(psi + (size_t)s * 304) + 2 * t;
        uint32_t u0 = p[0], u1 = p[1];
        a0 += __uint_as_float(u0 << 16);
        a1 += __uint_as_float(u0 & 0xffff0000u);
        a2 += __uint_as_float(u1 << 16);
        a3 += __uint_as_float(u1 & 0xffff0000u);
    }
    int f = 4 * t;
    f32x4 v = {0.1f * a0, 0.1f * a1, 0.1f * a2, 0.1f * a3};
    if (f < 64)       *(f32x4*)&out[(size_t)n * 64 + f] = v;
    else if (f < 160) *(f32x4*)&out[(size_t)N * 64 + (size_t)n * 96 + (f - 64)] = v;
    else              *(f32x4*)&out[(size_t)N * 160 + (size_t)n * 144 + (f - 160)] = v;
}

// -------------------------------------------------------------- launch ----
extern "C" void kernel_launch(void* const* d_in, const int* in_sizes, int n_in,
                              void* d_out, int out_size, void* d_ws, size_t ws_size,
                              hipStream_t stream) {
    const float* r_ij = (const float*)d_in[0];
    const float* x_a  = (const float*)d_in[1];
    const float* x_v  = (const float*)d_in[2];
    const float* x_d  = (const float*)d_in[3];
    const float* W_L0 = (const float*)d_in[4];
    const float* W_L1 = (const float*)d_in[5];
    const float* W_L2 = (const float*)d_in[6];
    const float* W000 = (const float*)d_in[7];
    const float* W110 = (const float*)d_in[8];
    const float* W220 = (const float*)d_in[9];
    const float* W011 = (const float*)d_in[10];
    const float* W101 = (const float*)d_in[11];
    const float* W121 = (const float*)d_in[12];
    const float* W211 = (const float*)d_in[13];
    const float* W022 = (const float*)d_in[14];
    const float* W202 = (const float*)d_in[15];
    const float* W112 = (const float*)d_in[16];
    const float* W222 = (const float*)d_in[17];
    const float* W111 = (const float*)d_in[18];
    const float* W212 = (const float*)d_in[19];
    const float* Wenc = (const float*)d_in[20];
    const float* benc = (const float*)d_in[21];
    const float* Wdir = (const float*)d_in[22];
    const float* W1   = (const float*)d_in[23];
    const float* b1   = (const float*)d_in[24];
    const float* W2   = (const float*)d_in[25];
    const float* b2   = (const float*)d_in[26];
    const float* W3   = (const float*)d_in[27];
    const float* b3   = (const float*)d_in[28];
    const int* src    = (const int*)d_in[29];
    const int* dst    = (const int*)d_in[30];

    const int E = in_sizes[29];
    const int N = in_sizes[1] / 64;

    // ws layout (padded P)
    float* Pa     = (float*)d_ws;                    // N*16
    float* Pv     = Pa + (size_t)N * 16;             // N*64 (stride-4 pad)
    float* Pd     = Pv + (size_t)N * 64;             // N*192 (stride-12 pad)
    bf16*  Wb     = (bf16*)(Pd + (size_t)N * 192);   // 45568 bf16
    int*   cnt    = (int*)(Wb + 45568);              // N
    int*   cur    = cnt + N;                         // N
    int*   rs     = cur + N;                         // N+1
    short* psi    = (short*)(rs + N + 1);            // E*304 bf16

    const bf16* Wa_p    = Wb;
    const bf16* Wv_p    = Wb + 4096;
    const bf16* Wd_p    = Wb + 7168;
    const bf16* Wb1_p   = Wb + 8704;
    const bf16* Wb2_p   = Wb + 16896;
    const bf16* Wb3_p   = Wb + 33280;
    const bf16* Wbdir_p = Wb + 41472;

    const int NPB = (N + 3) / 4;
    const int HB  = (E + 255) / 256;

    hipMemsetAsync(cnt, 0, (size_t)2 * N * sizeof(int), stream);   // cnt | cur
    prep_all<<<178 + NPB + HB, 256, 0, stream>>>(
        W000, W110, W220, W011, W101, W121, W211, W111,
        W022, W202, W112, W222, W212, W1, W2, W3, Wdir, Wb,
        x_a, x_v, x_d, W_L0, W_L1, W_L2, Pa, Pv, Pd, N, NPB,
        src, cnt, E);
    scan_rows<<<1, 256, 0, stream>>>(cnt, rs, N);
    edge_mfma<<<(E + 15) / 16, 256, 0, stream>>>(
        r_ij, Pa, Pv, Pd, Wenc, benc,
        Wa_p, Wv_p, Wd_p, Wb1_p, Wb2_p, Wb3_p, Wbdir_p,
        b1, b2, b3, src, dst, rs, cur, psi, E);
    gather<<<N, 128, 0, stream>>>(psi, rs, (float*)d_out, N);
}

// Round 14
// 227.673 us; speedup vs baseline: 2.2525x; 1.0105x over previous
//
#include <hip/hip_runtime.h>
#include <hip/hip_bf16.h>

typedef __hip_bfloat16 bf16;
typedef __attribute__((ext_vector_type(8))) short bf16x8;
typedef __attribute__((ext_vector_type(4))) float f32x4;

__device__ __forceinline__ void st_bf16(short* p, float v) {
    uint32_t u = __float_as_uint(v) + 0x8000u;
    *p = (short)(u >> 16);
}
__device__ __forceinline__ float bb2f(short s) {
    uint32_t u = ((uint32_t)(uint16_t)s) << 16;
    return __uint_as_float(u);
}

// ------------------------------------------------------------- prep_all ----
// blockIdx ranges: [0,178) prep_w | [178, 178+NPB) node_proj (padded P out)
//                  | rest: histogram of src
__global__ __launch_bounds__(256) void prep_all(
    const float* __restrict__ W000, const float* __restrict__ W110, const float* __restrict__ W220,
    const float* __restrict__ W011, const float* __restrict__ W101, const float* __restrict__ W121,
    const float* __restrict__ W211, const float* __restrict__ W111,
    const float* __restrict__ W022, const float* __restrict__ W202, const float* __restrict__ W112,
    const float* __restrict__ W222, const float* __restrict__ W212,
    const float* __restrict__ W1, const float* __restrict__ W2, const float* __restrict__ W3,
    const float* __restrict__ Wdir, bf16* __restrict__ wout,
    const float* __restrict__ xa, const float* __restrict__ xv, const float* __restrict__ xd,
    const float* __restrict__ WL0, const float* __restrict__ WL1, const float* __restrict__ WL2,
    float* __restrict__ Pa, float* __restrict__ Pv, float* __restrict__ Pd, int N, int NPB,
    const int* __restrict__ src, int* __restrict__ cnt, int E)
{
    int b = blockIdx.x;
    const int tid = threadIdx.x;
    if (b < 178) {
        // ---- weight packing (bf16, K zero-padded)
        int i = b * 256 + tid;
        if (i >= 45568) return;
        float v = 0.f;
        if (i < 4096) {
            int o = i >> 6, k = i & 63;
            if (k < 48) {
                int t = k >> 4, c = k & 15;
                const float* W = (t == 0) ? W000 : (t == 1) ? W110 : W220;
                v = W[o * 16 + c];
            }
        } else if (i < 7168) {
            int r = i - 4096, ch = r / 96, k = r % 96;
            if (k < 80) {
                int t = k >> 4, c = k & 15;
                const float* W = (t == 0) ? W011 : (t == 1) ? W101 : (t == 2) ? W121 : (t == 3) ? W211 : W111;
                v = W[ch * 16 + c];
            }
        } else if (i < 8704) {
            int r = i - 7168, ch = r / 96, k = r % 96;
            if (k < 80) {
                int t = k >> 4, c = k & 15;
                const float* W = (t == 0) ? W022 : (t == 1) ? W202 : (t == 2) ? W112 : (t == 3) ? W222 : W212;
                v = W[ch * 16 + c];
            }
        } else if (i < 16896) v = W1[i - 8704];
        else if (i < 33280) v = W2[i - 16896];
        else if (i < 41472) v = W3[i - 33280];
        else v = Wdir[i - 41472];
        wout[i] = __float2bfloat16(v);
        return;
    }
    b -= 178;
    if (b < NPB) {
        // ---- node projection, 4 nodes/block, padded output layouts
        __shared__ float sxa[256], sxv[384], sxd[576];
        const int n0 = b * 4;
        if (n0 + tid / 64 < N) sxa[tid] = xa[(size_t)n0 * 64 + tid];
        for (int i = tid; i < 384; i += 256) if (n0 + i / 96 < N)  sxv[i] = xv[(size_t)n0 * 96 + i];
        for (int i = tid; i < 576; i += 256) if (n0 + i / 144 < N) sxd[i] = xd[(size_t)n0 * 144 + i];
        __syncthreads();
        for (int o = tid; o < 832; o += 256) {
            int ln = o / 208, s = o % 208;
            int n = n0 + ln;
            if (n >= N) continue;
            if (s < 16) {
                const f32x4* w4 = (const f32x4*)(WL0 + s * 64);
                const f32x4* x4 = (const f32x4*)(sxa + ln * 64);
                f32x4 acc4 = {};
                #pragma unroll
                for (int d = 0; d < 16; ++d) {
                    f32x4 wv = w4[d], xv4 = x4[d];
                    acc4.x = fmaf(wv.x, xv4.x, acc4.x);
                    acc4.y = fmaf(wv.y, xv4.y, acc4.y);
                    acc4.z = fmaf(wv.z, xv4.z, acc4.z);
                    acc4.w = fmaf(wv.w, xv4.w, acc4.w);
                }
                Pa[(size_t)n * 16 + s] = (acc4.x + acc4.y) + (acc4.z + acc4.w);
            } else if (s < 64) {
                int idx = s - 16, c = idx / 3, i = idx % 3;
                float a = 0.f;
                const float* w = WL1 + c * 32;
                const float* x = sxv + ln * 96;
                for (int d = 0; d < 32; ++d) a += w[d] * x[d * 3 + i];
                Pv[(size_t)n * 64 + c * 4 + i] = a;
            } else {
                int idx = s - 64, c = idx / 9, ij = idx % 9;
                float a = 0.f;
                const float* w = WL2 + c * 16;
                const float* x = sxd + ln * 144;
                for (int d = 0; d < 16; ++d) a += w[d] * x[d * 9 + ij];
                Pd[(size_t)n * 192 + c * 12 + ij] = a;
            }
        }
        return;
    }
    b -= NPB;
    // ---- histogram of src
    int i = b * 256 + tid;
    if (i < E) atomicAdd(&cnt[src[i]], 1);
}

// --------------------------------------------------------------- CSR ----
__global__ void scan_rows(const int* __restrict__ cnt, int* __restrict__ rowstart, int N) {
    __shared__ int ps[256];
    int t = threadIdx.x;
    int chunk = (N + 255) / 256;
    int base = t * chunk;
    int s = 0;
    for (int i = 0; i < chunk; ++i) { int idx = base + i; if (idx < N) s += cnt[idx]; }
    ps[t] = s;
    __syncthreads();
    for (int off = 1; off < 256; off <<= 1) {
        int v = (t >= off) ? ps[t - off] : 0;
        __syncthreads();
        ps[t] += v;
        __syncthreads();
    }
    int run = (t > 0) ? ps[t - 1] : 0;
    for (int i = 0; i < chunk; ++i) {
        int idx = base + i;
        if (idx < N) { rowstart[idx] = run; run += cnt[idx]; }
    }
    if (t == 255) rowstart[N] = run;
}

// ---------------------------------------------------------- edge_mfma ----
// r13 structure (best known, byte-identical): 16 edges/block, natural order,
// ~32.3KB LDS, inline CSR slot.
__global__ __launch_bounds__(256) void edge_mfma(
    const float* __restrict__ r_ij,
    const float* __restrict__ Pa, const float* __restrict__ Pv, const float* __restrict__ Pd,
    const float* __restrict__ Wenc, const float* __restrict__ benc,
    const bf16* __restrict__ Wa, const bf16* __restrict__ Wv, const bf16* __restrict__ Wd,
    const bf16* __restrict__ Wb1, const bf16* __restrict__ Wb2,
    const bf16* __restrict__ Wb3, const bf16* __restrict__ Wbdir,
    const float* __restrict__ b1, const float* __restrict__ b2, const float* __restrict__ b3,
    const int* __restrict__ src, const int* __restrict__ dst,
    const int* __restrict__ rs, int* __restrict__ cur,
    short* __restrict__ psi, int E)
{
    __shared__ __align__(16) char smem[32320];
    short* SYA   = (short*)smem;            // [16][48]
    short* SYV   = (short*)(smem + 1536);   // [48][80]
    short* SYD   = (short*)(smem + 9216);   // [144][80]
    int*   SSLOT = (int*)(smem + 32256);    // [16]
    // phase-3 aliases (valid after b2)
    short* SPSIA = (short*)(smem + 1536);   // [16][72]
    short* SH1   = (short*)(smem + 3840);   // [16][136]
    short* SH2   = (short*)(smem + 8192);   // [16][136]
    short* SPSI  = (short*)(smem + 12544);  // [16][304]

    const int tid = threadIdx.x;
    const int e0 = blockIdx.x * 16;
    const bf16x8 z8 = {};

    // ---- phase 1: y-build. thread = (local edge le, channel c)
    {
        const int le = tid >> 4, c = tid & 15;
        const int e = e0 + le;
        if (e < E) {
            const int j = dst[e];
            if (c == 0) SSLOT[le] = rs[src[e]] + atomicAdd(&cur[src[e]], 1);
            float vx = 7.f * r_ij[e * 3 + 0];
            float vy = 7.f * r_ij[e * 3 + 1];
            float vz = 7.f * r_ij[e * 3 + 2];
            float nn = sqrtf(vx * vx + vy * vy + vz * vz);
            float ex = __expf(-2.f * nn);
            float th = (1.f - ex) * __builtin_amdgcn_rcpf(1.f + ex);
            float sc = th * __builtin_amdgcn_rcpf(nn + 1e-12f);
            float rr[3] = {vx * sc, vy * sc, vz * sc};
            float x8 = nn * (8.f / 7.f);
            float rad = benc[c];
            #pragma unroll
            for (int m = 0; m < 8; ++m) {
                float tt = x8 - (float)m;
                rad += __expf(-0.5f * tt * tt) * Wenc[c * 8 + m];
            }
            float xa = Pa[j * 16 + c];
            f32x4 pv4 = *(const f32x4*)(Pv + (size_t)j * 64 + c * 4);
            f32x4 pd0 = *(const f32x4*)(Pd + (size_t)j * 192 + c * 12);
            f32x4 pd1 = *(const f32x4*)(Pd + (size_t)j * 192 + c * 12 + 4);
            f32x4 pd2 = *(const f32x4*)(Pd + (size_t)j * 192 + c * 12 + 8);
            float xv[3] = {pv4[0], pv4[1], pv4[2]};
            float xd[9] = {pd0[0], pd0[1], pd0[2], pd0[3], pd1[0], pd1[1], pd1[2], pd1[3], pd2[0]};
            float dotv = xv[0] * rr[0] + xv[1] * rr[1] + xv[2] * rr[2];
            float mv[3];
            #pragma unroll
            for (int i = 0; i < 3; ++i)
                mv[i] = xd[i * 3] * rr[0] + xd[i * 3 + 1] * rr[1] + xd[i * 3 + 2] * rr[2];
            float quad = mv[0] * rr[0] + mv[1] * rr[1] + mv[2] * rr[2];
            st_bf16(&SYA[le * 48 + c],      xa * rad);
            st_bf16(&SYA[le * 48 + 16 + c], rad * dotv);
            st_bf16(&SYA[le * 48 + 32 + c], rad * quad);
            #pragma unroll
            for (int i = 0; i < 3; ++i) {
                int row = (le * 3 + i) * 80;
                int i1 = (i + 1) % 3, i2 = (i + 2) % 3;
                st_bf16(&SYV[row + c],      xa * rad * rr[i]);
                st_bf16(&SYV[row + 16 + c], rad * xv[i]);
                st_bf16(&SYV[row + 32 + c], rad * dotv * rr[i]);
                st_bf16(&SYV[row + 48 + c], rad * mv[i]);
                st_bf16(&SYV[row + 64 + c], rad * (xv[i1] * rr[i2] - xv[i2] * rr[i1]));
            }
            #pragma unroll
            for (int i = 0; i < 3; ++i) {
                int i1 = (i + 1) % 3, i2 = (i + 2) % 3;
                #pragma unroll
                for (int jj = 0; jj < 3; ++jj) {
                    int row = (le * 9 + i * 3 + jj) * 80;
                    st_bf16(&SYD[row + c],      xa * rad * rr[i] * rr[jj]);
                    st_bf16(&SYD[row + 16 + c], rad * xd[i * 3 + jj]);
                    st_bf16(&SYD[row + 32 + c], rad * xv[i] * rr[jj]);
                    st_bf16(&SYD[row + 48 + c], rad * mv[i] * rr[jj]);
                    st_bf16(&SYD[row + 64 + c], rad * (xd[i1 * 3 + jj] * rr[i2] - xd[i2 * 3 + jj] * rr[i1]));
                }
            }
        }
    }
    __syncthreads();   // b1: y ready

    // ---- phase 2: tensor GEMMs (accumulators persist across b2)
    const int wid = tid >> 6, lane = tid & 63;
    const int q16 = lane >> 4, r16 = lane & 15;

    f32x4 da[4] = {};
    f32x4 dv[3][2] = {};
    f32x4 dd[5] = {};
    const int mstart = (wid == 2) ? 0 : 5;
    const int mcnt = (wid == 2) ? 5 : 4;

    if (wid == 0) {
        bf16x8 af0 = *(const bf16x8*)&SYA[r16 * 48 + q16 * 8];
        bf16x8 af1 = z8;
        if (q16 < 2) af1 = *(const bf16x8*)&SYA[r16 * 48 + 32 + q16 * 8];
        #pragma unroll
        for (int n = 0; n < 4; ++n) {
            bf16x8 bf0 = *(const bf16x8*)((const short*)Wa + (n * 16 + r16) * 64 + q16 * 8);
            bf16x8 bf1 = *(const bf16x8*)((const short*)Wa + (n * 16 + r16) * 64 + 32 + q16 * 8);
            da[n] = __builtin_amdgcn_mfma_f32_16x16x32_bf16(af0, bf0, da[n], 0, 0, 0);
            da[n] = __builtin_amdgcn_mfma_f32_16x16x32_bf16(af1, bf1, da[n], 0, 0, 0);
        }
    } else if (wid == 1) {
        #pragma unroll
        for (int ks = 0; ks < 3; ++ks) {
            bf16x8 av[3], bv[2];
            #pragma unroll
            for (int m = 0; m < 3; ++m) {
                if (ks < 2) av[m] = *(const bf16x8*)&SYV[(m * 16 + r16) * 80 + ks * 32 + q16 * 8];
                else {
                    av[m] = z8;
                    if (q16 < 2) av[m] = *(const bf16x8*)&SYV[(m * 16 + r16) * 80 + 64 + q16 * 8];
                }
            }
            #pragma unroll
            for (int n = 0; n < 2; ++n)
                bv[n] = *(const bf16x8*)((const short*)Wv + (n * 16 + r16) * 96 + ks * 32 + q16 * 8);
            #pragma unroll
            for (int m = 0; m < 3; ++m)
                #pragma unroll
                for (int n = 0; n < 2; ++n)
                    dv[m][n] = __builtin_amdgcn_mfma_f32_16x16x32_bf16(av[m], bv[n], dv[m][n], 0, 0, 0);
        }
    } else {
        #pragma unroll
        for (int ks = 0; ks < 3; ++ks) {
            bf16x8 bf = *(const bf16x8*)((const short*)Wd + r16 * 96 + ks * 32 + q16 * 8);
            for (int mi = 0; mi < mcnt; ++mi) {
                bf16x8 af;
                if (ks < 2) af = *(const bf16x8*)&SYD[((mstart + mi) * 16 + r16) * 80 + ks * 32 + q16 * 8];
                else {
                    af = z8;
                    if (q16 < 2) af = *(const bf16x8*)&SYD[((mstart + mi) * 16 + r16) * 80 + 64 + q16 * 8];
                }
                dd[mi] = __builtin_amdgcn_mfma_f32_16x16x32_bf16(af, bf, dd[mi], 0, 0, 0);
            }
        }
    }
    __syncthreads();   // b2: y reads done, alias region reusable

    // ---- epilogues into aliased region
    if (wid == 0) {
        #pragma unroll
        for (int n = 0; n < 4; ++n)
            #pragma unroll
            for (int jj = 0; jj < 4; ++jj)
                st_bf16(&SPSIA[(q16 * 4 + jj) * 72 + n * 16 + r16], da[n][jj]);
    } else if (wid == 1) {
        #pragma unroll
        for (int m = 0; m < 3; ++m)
            #pragma unroll
            for (int n = 0; n < 2; ++n)
                #pragma unroll
                for (int jj = 0; jj < 4; ++jj) {
                    int row = m * 16 + q16 * 4 + jj;
                    int el = row / 3, i = row % 3;
                    st_bf16(&SPSI[el * 304 + 64 + (n * 16 + r16) * 3 + i], dv[m][n][jj]);
                }
    } else {
        for (int mi = 0; mi < mcnt; ++mi)
            #pragma unroll
            for (int jj = 0; jj < 4; ++jj) {
                int row = (mstart + mi) * 16 + q16 * 4 + jj;
                int el = row / 9, ij = row % 9;
                st_bf16(&SPSI[el * 304 + 160 + r16 * 9 + ij], dd[mi][jj]);
            }
    }
    __syncthreads();   // b3: psi_a + psi_v/d staged

    // ---- phase 3: fused MLP (M=16, waves split N)
    {
        f32x4 h1a[2] = {};
        #pragma unroll
        for (int ks = 0; ks < 2; ++ks) {
            bf16x8 af = *(const bf16x8*)&SPSIA[r16 * 72 + ks * 32 + q16 * 8];
            #pragma unroll
            for (int n = 0; n < 2; ++n) {
                int col = wid * 32 + n * 16 + r16;
                bf16x8 bf = *(const bf16x8*)((const short*)Wb1 + col * 64 + ks * 32 + q16 * 8);
                h1a[n] = __builtin_amdgcn_mfma_f32_16x16x32_bf16(af, bf, h1a[n], 0, 0, 0);
            }
        }
        #pragma unroll
        for (int n = 0; n < 2; ++n) {
            int col = wid * 32 + n * 16 + r16;
            float bias = b1[col];
            #pragma unroll
            for (int jj = 0; jj < 4; ++jj) {
                float v = h1a[n][jj] + bias;
                v = v >= 0.f ? v : 0.1f * v;
                st_bf16(&SH1[(q16 * 4 + jj) * 136 + col], v);
            }
        }
    }
    __syncthreads();   // b4: h1 ready
    {
        f32x4 h2a[2] = {};
        #pragma unroll
        for (int ks = 0; ks < 4; ++ks) {
            bf16x8 af = *(const bf16x8*)&SH1[r16 * 136 + ks * 32 + q16 * 8];
            #pragma unroll
            for (int n = 0; n < 2; ++n) {
                int col = wid * 32 + n * 16 + r16;
                bf16x8 bf = *(const bf16x8*)((const short*)Wb2 + col * 128 + ks * 32 + q16 * 8);
                h2a[n] = __builtin_amdgcn_mfma_f32_16x16x32_bf16(af, bf, h2a[n], 0, 0, 0);
            }
        }
        #pragma unroll
        for (int n = 0; n < 2; ++n) {
            int col = wid * 32 + n * 16 + r16;
            float bias = b2[col];
            #pragma unroll
            for (int jj = 0; jj < 4; ++jj) {
                float v = h2a[n][jj] + bias;
                v = v >= 0.f ? v : 0.1f * v;
                st_bf16(&SH2[(q16 * 4 + jj) * 136 + col], v);
            }
        }
    }
    __syncthreads();   // b5: h2 ready
    {
        f32x4 o3 = {};
        const int col3 = wid * 16 + r16;
        #pragma unroll
        for (int ks = 0; ks < 4; ++ks) {
            bf16x8 af = *(const bf16x8*)&SH2[r16 * 136 + ks * 32 + q16 * 8];
            bf16x8 bf = *(const bf16x8*)((const short*)Wb3 + col3 * 128 + ks * 32 + q16 * 8);
            o3 = __builtin_amdgcn_mfma_f32_16x16x32_bf16(af, bf, o3, 0, 0, 0);
        }
        #pragma unroll
        for (int ks = 0; ks < 2; ++ks) {
            bf16x8 af = *(const bf16x8*)&SPSIA[r16 * 72 + ks * 32 + q16 * 8];
            bf16x8 bf = *(const bf16x8*)((const short*)Wbdir + col3 * 64 + ks * 32 + q16 * 8);
            o3 = __builtin_amdgcn_mfma_f32_16x16x32_bf16(af, bf, o3, 0, 0, 0);
        }
        float bias = b3[col3];
        #pragma unroll
        for (int jj = 0; jj < 4; ++jj) {
            int row = q16 * 4 + jj;
            float v = o3[jj] + bias + bb2f(SPSIA[row * 72 + col3]);
            st_bf16(&SPSI[row * 304 + col3], v);
        }
    }
    __syncthreads();   // b6: SPSI complete

    // ---- coalesced psi-row store at CSR slot
    {
        const uint32_t* S32 = (const uint32_t*)SPSI;
        uint32_t* P32 = (uint32_t*)psi;
        for (int idx2 = tid; idx2 < 16 * 152; idx2 += 256) {
            int le = idx2 / 152, k = idx2 - le * 152;
            if (e0 + le < E)
                P32[(size_t)SSLOT[le] * 152 + k] = S32[le * 152 + k];
        }
    }
}

// -------------------------------------------------------------- gather ----
// 4 nodes per 256-thread block (1 wave each); lane<38 reads uint4 (16B) per
// row -> 8 f32 outputs per lane -> two f32x4 stores. Segment boundaries
// (64,160) are multiples of 8, so each lane's 8 outputs stay in one segment.
__global__ __launch_bounds__(256) void gather(
    const short* __restrict__ psi, const int* __restrict__ rowstart,
    float* __restrict__ out, int N) {
    const int wid = threadIdx.x >> 6, lane = threadIdx.x & 63;
    const int n = blockIdx.x * 4 + wid;
    if (n >= N || lane >= 38) return;
    const int s0 = rowstart[n], s1 = rowstart[n + 1];
    float a0 = 0.f, a1 = 0.f, a2 = 0.f, a3 = 0.f, a4 = 0.f, a5 = 0.f, a6 = 0.f, a7 = 0.f;
    for (int s = s0; s < s1; ++s) {
        const uint4 u = *(const uint4*)((const uint32_t*)(psi + (size_t)s * 304) + 4 * lane);
        a0 += __uint_as_float(u.x << 16);
        a1 += __uint_as_float(u.x & 0xffff0000u);
        a2 += __uint_as_float(u.y << 16);
        a3 += __uint_as_float(u.y & 0xffff0000u);
        a4 += __uint_as_float(u.z << 16);
        a5 += __uint_as_float(u.z & 0xffff0000u);
        a6 += __uint_as_float(u.w << 16);
        a7 += __uint_as_float(u.w & 0xffff0000u);
    }
    const int f = 8 * lane;
    f32x4 v0 = {0.1f * a0, 0.1f * a1, 0.1f * a2, 0.1f * a3};
    f32x4 v1 = {0.1f * a4, 0.1f * a5, 0.1f * a6, 0.1f * a7};
    float* base;
    if (f < 64)       base = out + (size_t)n * 64 + f;
    else if (f < 160) base = out + (size_t)N * 64 + (size_t)n * 96 + (f - 64);
    else              base = out + (size_t)N * 160 + (size_t)n * 144 + (f - 160);
    *(f32x4*)base = v0;
    *(f32x4*)(base + 4) = v1;
}

// -------------------------------------------------------------- launch ----
extern "C" void kernel_launch(void* const* d_in, const int* in_sizes, int n_in,
                              void* d_out, int out_size, void* d_ws, size_t ws_size,
                              hipStream_t stream) {
    const float* r_ij = (const float*)d_in[0];
    const float* x_a  = (const float*)d_in[1];
    const float* x_v  = (const float*)d_in[2];
    const float* x_d  = (const float*)d_in[3];
    const float* W_L0 = (const float*)d_in[4];
    const float* W_L1 = (const float*)d_in[5];
    const float* W_L2 = (const float*)d_in[6];
    const float* W000 = (const float*)d_in[7];
    const float* W110 = (const float*)d_in[8];
    const float* W220 = (const float*)d_in[9];
    const float* W011 = (const float*)d_in[10];
    const float* W101 = (const float*)d_in[11];
    const float* W121 = (const float*)d_in[12];
    const float* W211 = (const float*)d_in[13];
    const float* W022 = (const float*)d_in[14];
    const float* W202 = (const float*)d_in[15];
    const float* W112 = (const float*)d_in[16];
    const float* W222 = (const float*)d_in[17];
    const float* W111 = (const float*)d_in[18];
    const float* W212 = (const float*)d_in[19];
    const float* Wenc = (const float*)d_in[20];
    const float* benc = (const float*)d_in[21];
    const float* Wdir = (const float*)d_in[22];
    const float* W1   = (const float*)d_in[23];
    const float* b1   = (const float*)d_in[24];
    const float* W2   = (const float*)d_in[25];
    const float* b2   = (const float*)d_in[26];
    const float* W3   = (const float*)d_in[27];
    const float* b3   = (const float*)d_in[28];
    const int* src    = (const int*)d_in[29];
    const int* dst    = (const int*)d_in[30];

    const int E = in_sizes[29];
    const int N = in_sizes[1] / 64;

    // ws layout (padded P)
    float* Pa     = (float*)d_ws;                    // N*16
    float* Pv     = Pa + (size_t)N * 16;             // N*64 (stride-4 pad)
    float* Pd     = Pv + (size_t)N * 64;             // N*192 (stride-12 pad)
    bf16*  Wb     = (bf16*)(Pd + (size_t)N * 192);   // 45568 bf16
    int*   cnt    = (int*)(Wb + 45568);              // N
    int*   cur    = cnt + N;                         // N
    int*   rs     = cur + N;                         // N+1
    short* psi    = (short*)(rs + N + 1);            // E*304 bf16

    const bf16* Wa_p    = Wb;
    const bf16* Wv_p    = Wb + 4096;
    const bf16* Wd_p    = Wb + 7168;
    const bf16* Wb1_p   = Wb + 8704;
    const bf16* Wb2_p   = Wb + 16896;
    const bf16* Wb3_p   = Wb + 33280;
    const bf16* Wbdir_p = Wb + 41472;

    const int NPB = (N + 3) / 4;
    const int HB  = (E + 255) / 256;

    hipMemsetAsync(cnt, 0, (size_t)2 * N * sizeof(int), stream);   // cnt | cur
    prep_all<<<178 + NPB + HB, 256, 0, stream>>>(
        W000, W110, W220, W011, W101, W121, W211, W111,
        W022, W202, W112, W222, W212, W1, W2, W3, Wdir, Wb,
        x_a, x_v, x_d, W_L0, W_L1, W_L2, Pa, Pv, Pd, N, NPB,
        src, cnt, E);
    scan_rows<<<1, 256, 0, stream>>>(cnt, rs, N);
    edge_mfma<<<(E + 15) / 16, 256, 0, stream>>>(
        r_ij, Pa, Pv, Pd, Wenc, benc,
        Wa_p, Wv_p, Wd_p, Wb1_p, Wb2_p, Wb3_p, Wbdir_p,
        b1, b2, b3, src, dst, rs, cur, psi, E);
    gather<<<(N + 3) / 4, 256, 0, stream>>>(psi, rs, (float*)d_out, N);
}